// Round 11
// baseline (1901.952 us; speedup 1.0000x reference)
//
#include <hip/hip_runtime.h>

typedef unsigned short ushort_t;
typedef __bf16 bf16x8 __attribute__((ext_vector_type(8)));
typedef float f32x4 __attribute__((ext_vector_type(4)));

#define DEV __device__ __forceinline__

DEV ushort_t f2bf(float x) {
  union { float f; unsigned u; } v; v.f = x;
  unsigned r = v.u + 0x7FFFu + ((v.u >> 16) & 1u);
  return (ushort_t)(r >> 16);
}
DEV int sid_of(int l) { return l < 5 ? 0 : (l < 21 ? 1 : (l < 85 ? 2 : 3)); }
DEV float fast_tanh(float u) { return 1.0f - 2.0f / (__expf(2.0f * u) + 1.0f); }
DEV float gelu_f(float x) {
  float u = 0.7978845608028654f * (x + 0.044715f * x * x * x);
  return 0.5f * x * (1.0f + fast_tanh(u));
}
DEV float silu_f(float x) { return x / (1.0f + __expf(-x)); }
DEV f32x4 mfma16(bf16x8 a, bf16x8 b, f32x4 c) {
  return __builtin_amdgcn_mfma_f32_16x16x32_bf16(a, b, c, 0, 0, 0);
}
DEV void gload16(const void* src, void* dst) {
  __builtin_amdgcn_global_load_lds(
      (const __attribute__((address_space(1))) void*)(uintptr_t)src,
      (__attribute__((address_space(3))) void*)(uintptr_t)dst, 16, 0, 0);
}

// ---------------- cond gather + x row 0 ----------------
__global__ __launch_bounds__(256) void k_cond_x0(
    const int* __restrict__ labels, const float* __restrict__ class_emb,
    const float* __restrict__ pos, const float* __restrict__ semb,
    float* __restrict__ cond, float* __restrict__ x) {
  int b = blockIdx.x, t = threadIdx.x;
  int lab = labels[b];
  float4 cv = *(const float4*)&class_emb[(size_t)lab * 1024 + t * 4];
  *(float4*)&cond[(size_t)b * 1024 + t * 4] = cv;
  float4 pv = *(const float4*)&pos[t * 4];
  float4 sv = *(const float4*)&semb[t * 4];
  float4 xv;
  xv.x = cv.x + pv.x + sv.x; xv.y = cv.y + pv.y + sv.y;
  xv.z = cv.z + pv.z + sv.z; xv.w = cv.w + pv.w + sv.w;
  *(float4*)&x[(size_t)b * 341 * 1024 + t * 4] = xv;
}

// ---------------- f32 -> bf16 convert ----------------
__global__ __launch_bounds__(256) void k_convert(const float* __restrict__ src,
                                                 ushort_t* __restrict__ dst, int n4) {
  int i = blockIdx.x * 256 + threadIdx.x;
  if (i < n4) {
    float4 v = *(const float4*)&src[(size_t)i * 4];
    uint2 pk;
    pk.x = (unsigned)f2bf(v.x) | ((unsigned)f2bf(v.y) << 16);
    pk.y = (unsigned)f2bf(v.z) | ((unsigned)f2bf(v.w) << 16);
    *(uint2*)&dst[(size_t)i * 4] = pk;
  }
}

// ---------------- transpose f32 [K][N] -> bf16 [N][K], batched over z ----------------
__global__ __launch_bounds__(256) void k_transpose(const float* __restrict__ src,
                                                   ushort_t* __restrict__ dst, int K, int N) {
  __shared__ ushort_t tile[32][33];
  int z = blockIdx.z;
  src += (size_t)z * K * N;
  dst += (size_t)z * K * N;
  int k0 = blockIdx.y * 32, n0 = blockIdx.x * 32;
  int t = threadIdx.x;
  int r = t >> 3, c = (t & 7) * 4;
  float4 v = *(const float4*)&src[(size_t)(k0 + r) * N + n0 + c];
  tile[r][c] = f2bf(v.x); tile[r][c + 1] = f2bf(v.y);
  tile[r][c + 2] = f2bf(v.z); tile[r][c + 3] = f2bf(v.w);
  __syncthreads();
  ushort_t o0 = tile[c][r], o1 = tile[c + 1][r], o2 = tile[c + 2][r], o3 = tile[c + 3][r];
  uint2 pk;
  pk.x = (unsigned)o0 | ((unsigned)o1 << 16);
  pk.y = (unsigned)o2 | ((unsigned)o3 << 16);
  *(uint2*)&dst[(size_t)(n0 + r) * K + k0 + c] = pk;
}

// ---------------- adaLN GEMM ----------------
__global__ __launch_bounds__(256) void k_ada(const float* __restrict__ cond,
    const float* __restrict__ ada_W, const float* __restrict__ ada_b,
    const float* __restrict__ hada_W, const float* __restrict__ hada_b,
    float* __restrict__ ada_out, float* __restrict__ hada_out) {
  int gy = blockIdx.y;
  bool head = (gy == 8);
  int Nw = head ? 2048 : 6144;
  int n0 = blockIdx.x * 64;
  if (n0 >= Nw) return;
  __shared__ float sc[8 * 1024];
  __shared__ float red[4][64][8];
  int t = threadIdx.x;
  for (int i = t; i < 2048; i += 256) {
    float4 cv = *(const float4*)&cond[(size_t)i * 4];
    float* d = &sc[i * 4];
    d[0] = silu_f(cv.x); d[1] = silu_f(cv.y); d[2] = silu_f(cv.z); d[3] = silu_f(cv.w);
  }
  __syncthreads();
  const float* W = head ? hada_W : ada_W + (size_t)gy * 1024 * 6144;
  const float* bs = head ? hada_b : ada_b + (size_t)gy * 6144;
  float* op = head ? hada_out : ada_out + (size_t)gy * 8 * 6144;
  int col = n0 + (t & 63), kq = t >> 6;
  float acc[8] = {0.f, 0.f, 0.f, 0.f, 0.f, 0.f, 0.f, 0.f};
  for (int k = kq * 256; k < kq * 256 + 256; ++k) {
    float wv = W[(size_t)k * Nw + col];
#pragma unroll
    for (int b2 = 0; b2 < 8; ++b2) acc[b2] += wv * sc[b2 * 1024 + k];
  }
#pragma unroll
  for (int b2 = 0; b2 < 8; ++b2) red[kq][t & 63][b2] = acc[b2];
  __syncthreads();
  if (t < 64) {
    int colc = n0 + t;
    float bias = bs[colc];
#pragma unroll
    for (int b2 = 0; b2 < 8; ++b2) {
      float v = red[0][t][b2] + red[1][t][b2] + red[2][t][b2] + red[3][t][b2] + bias;
      op[(size_t)b2 * Nw + colc] = v;
    }
  }
}

// ---------------- LN + modulate -> bf16 ----------------
__global__ __launch_bounds__(256) void k_ln(const float* __restrict__ x,
    ushort_t* __restrict__ hout, const float* __restrict__ ada,
    int stride, int soff, int shoff) {
  int row = blockIdx.x, t = threadIdx.x;
  int b = row / 341;
  const float* xr = x + (size_t)row * 1024;
  float4 xv = *(const float4*)&xr[t * 4];
  float s = xv.x + xv.y + xv.z + xv.w;
  float ss = xv.x * xv.x + xv.y * xv.y + xv.z * xv.z + xv.w * xv.w;
#pragma unroll
  for (int off = 1; off < 64; off <<= 1) { s += __shfl_xor(s, off); ss += __shfl_xor(ss, off); }
  __shared__ float red[8];
  int w = t >> 6, lane = t & 63;
  if (lane == 0) { red[w] = s; red[w + 4] = ss; }
  __syncthreads();
  s = red[0] + red[1] + red[2] + red[3];
  ss = red[4] + red[5] + red[6] + red[7];
  float mean = s * (1.f / 1024.f);
  float var = ss * (1.f / 1024.f) - mean * mean;
  float rstd = rsqrtf(var + 1e-6f);
  const float* ar = ada + (size_t)b * stride;
  float xe[4] = {xv.x, xv.y, xv.z, xv.w};
  ushort_t tmp[4];
#pragma unroll
  for (int j = 0; j < 4; ++j) {
    int n = t * 4 + j;
    float val = (xe[j] - mean) * rstd * (1.f + ar[soff + n]) + ar[shoff + n];
    tmp[j] = f2bf(val);
  }
  uint2 pk;
  pk.x = (unsigned)tmp[0] | ((unsigned)tmp[1] << 16);
  pk.y = (unsigned)tmp[2] | ((unsigned)tmp[3] << 16);
  *(uint2*)&hout[(size_t)row * 1024 + t * 4] = pk;
}

// ---------------- fused residual-combine + LN + modulate (fc2 tail) ----------------
__global__ __launch_bounds__(256) void k_comb_ln(
    const float* __restrict__ p, const float* __restrict__ bias,
    const float* __restrict__ adag, int goff,
    float* __restrict__ x, const float* __restrict__ adaln,
    int lnstride, int soff, int shoff,
    ushort_t* __restrict__ hout) {
  int row = blockIdx.x, t = threadIdx.x;
  int b = row / 341;
  int c = t * 4;
  float4 s4 = *(const float4*)&p[(size_t)row * 1024 + c];
  float4 q2 = *(const float4*)&p[(size_t)2728 * 1024 + (size_t)row * 1024 + c];
  s4.x += q2.x; s4.y += q2.y; s4.z += q2.z; s4.w += q2.w;
  float4 bv = *(const float4*)&bias[c];
  const float* gr = adag + (size_t)b * 6144 + goff + c;
  float4 xv = *(float4*)&x[(size_t)row * 1024 + c];
  xv.x += gr[0] * (s4.x + bv.x);
  xv.y += gr[1] * (s4.y + bv.y);
  xv.z += gr[2] * (s4.z + bv.z);
  xv.w += gr[3] * (s4.w + bv.w);
  *(float4*)&x[(size_t)row * 1024 + c] = xv;
  float sm = xv.x + xv.y + xv.z + xv.w;
  float ss = xv.x * xv.x + xv.y * xv.y + xv.z * xv.z + xv.w * xv.w;
#pragma unroll
  for (int off = 1; off < 64; off <<= 1) { sm += __shfl_xor(sm, off); ss += __shfl_xor(ss, off); }
  __shared__ float red[8];
  int w = t >> 6, lane = t & 63;
  if (lane == 0) { red[w] = sm; red[w + 4] = ss; }
  __syncthreads();
  sm = red[0] + red[1] + red[2] + red[3];
  ss = red[4] + red[5] + red[6] + red[7];
  float mean = sm * (1.f / 1024.f);
  float var = ss * (1.f / 1024.f) - mean * mean;
  float rstd = rsqrtf(var + 1e-6f);
  const float* ar = adaln + (size_t)b * lnstride;
  float xe[4] = {xv.x, xv.y, xv.z, xv.w};
  ushort_t tmp[4];
#pragma unroll
  for (int j = 0; j < 4; ++j) {
    int n = c + j;
    float val = (xe[j] - mean) * rstd * (1.f + ar[soff + n]) + ar[shoff + n];
    tmp[j] = f2bf(val);
  }
  uint2 pk;
  pk.x = (unsigned)tmp[0] | ((unsigned)tmp[1] << 16);
  pk.y = (unsigned)tmp[2] | ((unsigned)tmp[3] << 16);
  *(uint2*)&hout[(size_t)row * 1024 + c] = pk;
}

// ---------------- main GEMM: 3-buffer / 1-barrier (R9, proven) ----------------
// EPI 1: xres += aux*v   EPI 2: bfout=gelu(v)  EPI 4: patch-embed
// EPI 6: qkv+qknorm      EPI 7: f32 partial at fout + z*M*N
template <int EPI, int BM>
__global__ __launch_bounds__(256, 3) void k_gemm(
    const ushort_t* __restrict__ A, const ushort_t* __restrict__ Bt,
    const float* __restrict__ bias, float* __restrict__ fout,
    ushort_t* __restrict__ bfout, const float* __restrict__ aux,
    float* __restrict__ xres, const float* __restrict__ pos,
    const float* __restrict__ semb, int M, int N, int K, int KS) {
  constexpr int NI = (BM == 128) ? 4 : 2;
  constexpr int WNB = (BM == 128) ? 64 : 32;
  __shared__ ushort_t aT[3][BM * 32];
  __shared__ ushort_t bT[3][128 * 32];
  int tid = threadIdx.x;
  int lane = tid & 63, w = tid >> 6;
  int WR = (BM == 128) ? (w >> 1) : 0;
  int WC = (BM == 128) ? (w & 1) : w;

  int gx = gridDim.x;
  int nwg = gx * gridDim.y;
  int orig = blockIdx.y * gx + blockIdx.x;
  int q = nwg >> 3, r8 = nwg & 7;
  int xcd = orig & 7, idx = orig >> 3;
  int lin = (xcd < r8 ? xcd * (q + 1) : r8 * (q + 1) + (xcd - r8) * q) + idx;
  int bx = lin % gx, by = lin / gx;

  int m0 = by * BM, n0 = bx * 128;
  int kbase = blockIdx.z * KS;
  f32x4 acc[4][NI];
#pragma unroll
  for (int i = 0; i < 4; ++i)
#pragma unroll
    for (int j = 0; j < NI; ++j) acc[i][j] = (f32x4){0.f, 0.f, 0.f, 0.f};

  int lrow = lane & 15;
  int csw = (lrow >> 1) & 3;
  int coff = ((lane >> 4) ^ csw) * 8;

  int s_row0 = tid >> 2, s_u = tid & 3;
  int s_c = s_u ^ ((s_row0 >> 1) & 3);
  int aR0 = m0 + s_row0; if (aR0 > M - 1) aR0 = M - 1;
  int bR0 = n0 + s_row0; if (bR0 > N - 1) bR0 = N - 1;
  int aR1 = m0 + s_row0 + 64; if (aR1 > M - 1) aR1 = M - 1;
  int bR1 = n0 + s_row0 + 64; if (bR1 > N - 1) bR1 = N - 1;
  const ushort_t* aSrc0 = A + (size_t)aR0 * K + kbase + s_c * 8;
  const ushort_t* aSrc1 = A + (size_t)aR1 * K + kbase + s_c * 8;
  const ushort_t* bSrc0 = Bt + (size_t)bR0 * K + kbase + s_c * 8;
  const ushort_t* bSrc1 = Bt + (size_t)bR1 * K + kbase + s_c * 8;
  int slot0 = w * 512, slot1 = 2048 + w * 512;

  int nsteps = KS >> 5;
  auto STAGE = [&](int k0, int buf) {
    gload16(aSrc0 + k0, &aT[buf][slot0]);
    if constexpr (BM == 128) gload16(aSrc1 + k0, &aT[buf][slot1]);
    gload16(bSrc0 + k0, &bT[buf][slot0]);
    gload16(bSrc1 + k0, &bT[buf][slot1]);
  };

  STAGE(0, 0);
  int cur = 0;
  for (int s = 0; s < nsteps; ++s) {
    int nb = cur + 1; if (nb == 3) nb = 0;
    int kn = (s + 1 < nsteps) ? ((s + 1) << 5) : 0;
    STAGE(kn, nb);
    if constexpr (BM == 128)
      asm volatile("s_waitcnt vmcnt(4)" ::: "memory");
    else
      asm volatile("s_waitcnt vmcnt(3)" ::: "memory");
    __builtin_amdgcn_sched_barrier(0);
    __builtin_amdgcn_s_barrier();
    __builtin_amdgcn_sched_barrier(0);
    bf16x8 af[4], bb[NI];
#pragma unroll
    for (int mi = 0; mi < 4; ++mi)
      af[mi] = *(const bf16x8*)&aT[cur][(WR * 64 + mi * 16 + lrow) * 32 + coff];
#pragma unroll
    for (int ni = 0; ni < NI; ++ni)
      bb[ni] = *(const bf16x8*)&bT[cur][(WC * WNB + ni * 16 + lrow) * 32 + coff];
#pragma unroll
    for (int mi = 0; mi < 4; ++mi)
#pragma unroll
      for (int ni = 0; ni < NI; ++ni)
        acc[mi][ni] = mfma16(af[mi], bb[ni], acc[mi][ni]);
    cur = nb;
  }

  if constexpr (EPI == 6) {
    int nb = n0 + WC * 64;
    int gh = nb >> 6;
    float qse = (gh < 16) ? __expf(aux[gh]) : 1.0f;
    bool dn = gh < 32;
#pragma unroll
    for (int mi = 0; mi < 4; ++mi) {
#pragma unroll
      for (int r = 0; r < 4; ++r) {
        float vv[4]; float ss = 0.f;
#pragma unroll
        for (int ni = 0; ni < 4; ++ni) {
          vv[ni] = acc[mi][ni][r] + bias[nb + ni * 16 + lrow];
          ss += vv[ni] * vv[ni];
        }
        if (dn) {
          ss += __shfl_xor(ss, 1); ss += __shfl_xor(ss, 2);
          ss += __shfl_xor(ss, 4); ss += __shfl_xor(ss, 8);
          float rn = qse / fmaxf(sqrtf(ss), 1e-12f);
#pragma unroll
          for (int ni = 0; ni < 4; ++ni) vv[ni] *= rn;
        }
        int gm = m0 + WR * 64 + mi * 16 + (lane >> 4) * 4 + r;
        if (gm < M) {
#pragma unroll
          for (int ni = 0; ni < 4; ++ni)
            bfout[(size_t)gm * N + nb + ni * 16 + lrow] = f2bf(vv[ni]);
        }
      }
    }
  } else {
#pragma unroll
    for (int mi = 0; mi < 4; ++mi) {
#pragma unroll
      for (int ni = 0; ni < NI; ++ni) {
#pragma unroll
        for (int r = 0; r < 4; ++r) {
          int gm = m0 + WR * 64 + mi * 16 + (lane >> 4) * 4 + r;
          int gn = n0 + WC * WNB + ni * 16 + lrow;
          if (gm >= M || gn >= N) continue;
          if constexpr (EPI == 7) {
            fout[(size_t)blockIdx.z * M * N + (size_t)gm * N + gn] = acc[mi][ni][r];
          } else {
            float v = acc[mi][ni][r] + bias[gn];
            if constexpr (EPI == 1) {
              int b = gm / 341;
              xres[(size_t)gm * 1024 + gn] += aux[(size_t)b * 6144 + gn] * v;
            } else if constexpr (EPI == 2) {
              bfout[(size_t)gm * N + gn] = f2bf(gelu_f(v));
            } else if constexpr (EPI == 4) {
              int b = gm / 340, l = gm % 340 + 1;
              float val = v + pos[(size_t)l * 1024 + gn] + semb[(size_t)sid_of(l) * 1024 + gn];
              xres[((size_t)(b * 341 + l)) * 1024 + gn] = val;
            }
          }
        }
      }
    }
  }
}

// ---------------- 256x256 8-phase GEMM (T2+T3+T4+T5), BK=64, 512 thr ----------------
// Phases per K-tile: p0{bb+af reads, stage B0,B1} p1{af, stage B2,B3, vmcnt(4)}
// p2{af, stage A0,A2} p3{af, stage A1,A3, vmcnt(2)}; barrier each phase end.
// Needed-by: B0-3,A0,A2 before p0 (guarded by p3's vmcnt(2)+barrier);
// A1,A3 before p2 (guarded by p1's vmcnt(4)+barrier).
// Swizzle: LDS rows 128B/8 chunks; chunk ^= (row&7); inverse on global source.
// EPI 2: bfout=gelu(v)+bias   EPI 6: qkv + fused qk-norm
#define PHASE_MFMA(p)                                                         \
  {                                                                           \
    bf16x8 af[2][2];                                                          \
    _Pragma("unroll")                                                         \
    for (int i = 0; i < 2; ++i)                                               \
      _Pragma("unroll")                                                       \
      for (int kk = 0; kk < 2; ++kk)                                          \
        af[i][kk] = *(const bf16x8*)&aT[cur][                                 \
            (WR * 128 + (2 * (p) + i) * 16 + lrow) * 64 +                     \
            ((kk * 4 + (lane >> 4)) ^ csw) * 8];                              \
    __builtin_amdgcn_s_setprio(1);                                            \
    _Pragma("unroll")                                                         \
    for (int i = 0; i < 2; ++i)                                               \
      _Pragma("unroll")                                                       \
      for (int ni = 0; ni < 4; ++ni)                                          \
        _Pragma("unroll")                                                     \
        for (int kk = 0; kk < 2; ++kk)                                        \
          acc[2 * (p) + i][ni] =                                              \
              mfma16(af[i][kk], bb[ni][kk], acc[2 * (p) + i][ni]);            \
    __builtin_amdgcn_s_setprio(0);                                            \
  }

template <int EPI>
__global__ __launch_bounds__(512, 2) void k_gemm8(
    const ushort_t* __restrict__ A, const ushort_t* __restrict__ Bt,
    const float* __restrict__ bias, ushort_t* __restrict__ bfout,
    const float* __restrict__ aux, int M, int N, int K) {
  __shared__ ushort_t aT[2][256 * 64];
  __shared__ ushort_t bT[2][256 * 64];
  int tid = threadIdx.x;
  int lane = tid & 63, w = tid >> 6;
  int WR = w >> 2, WC = w & 3;

  int gx = gridDim.x;
  int nwg = gx * gridDim.y;
  int orig = blockIdx.y * gx + blockIdx.x;
  int q = nwg >> 3, r8 = nwg & 7;
  int xcd = orig & 7, idx = orig >> 3;
  int lin = (xcd < r8 ? xcd * (q + 1) : r8 * (q + 1) + (xcd - r8) * q) + idx;
  int bx = lin % gx, by = lin / gx;
  int m0 = by * 256, n0 = bx * 256;

  f32x4 acc[8][4];
#pragma unroll
  for (int i = 0; i < 8; ++i)
#pragma unroll
    for (int j = 0; j < 4; ++j) acc[i][j] = (f32x4){0.f, 0.f, 0.f, 0.f};

  int lrow = lane & 15;
  int csw = lrow & 7;  // read-side chunk swizzle (row&7)

  // staging: thread covers (row sR within sweep, chunk lane&7); sweep = 64 rows
  int sR = w * 8 + (lane >> 3);
  int colOff = ((lane & 7) ^ ((lane >> 3) & 7)) * 8;  // inverse swizzle on source
  int rowA[4], rowB[4];
#pragma unroll
  for (int s = 0; s < 4; ++s) {
    int ra = m0 + s * 64 + sR; rowA[s] = ra > M - 1 ? M - 1 : ra;
    int rb = n0 + s * 64 + sR; rowB[s] = rb > N - 1 ? N - 1 : rb;
  }
  int ldsw = w * 512;  // wave-uniform elem offset within sweep block

  int NT = K >> 6;
  // prologue: tile 0 -> buf0, order B0..B3, A0, A2, A1, A3; leave A1,A3 in flight
  gload16(Bt + (size_t)rowB[0] * K + colOff, &bT[0][0 * 4096 + ldsw]);
  gload16(Bt + (size_t)rowB[1] * K + colOff, &bT[0][1 * 4096 + ldsw]);
  gload16(Bt + (size_t)rowB[2] * K + colOff, &bT[0][2 * 4096 + ldsw]);
  gload16(Bt + (size_t)rowB[3] * K + colOff, &bT[0][3 * 4096 + ldsw]);
  gload16(A + (size_t)rowA[0] * K + colOff, &aT[0][0 * 4096 + ldsw]);
  gload16(A + (size_t)rowA[2] * K + colOff, &aT[0][2 * 4096 + ldsw]);
  gload16(A + (size_t)rowA[1] * K + colOff, &aT[0][1 * 4096 + ldsw]);
  gload16(A + (size_t)rowA[3] * K + colOff, &aT[0][3 * 4096 + ldsw]);
  asm volatile("s_waitcnt vmcnt(2)" ::: "memory");
  __builtin_amdgcn_sched_barrier(0);
  __builtin_amdgcn_s_barrier();
  __builtin_amdgcn_sched_barrier(0);

  for (int kt = 0; kt < NT; ++kt) {
    int cur = kt & 1, nxt = cur ^ 1;
    int kn = (kt + 1 < NT) ? ((kt + 1) << 6) : 0;  // dummy wrap keeps counts uniform
    bf16x8 bb[4][2];
    // ---- phase 0 ----
    gload16(Bt + (size_t)rowB[0] * K + kn + colOff, &bT[nxt][0 * 4096 + ldsw]);
    gload16(Bt + (size_t)rowB[1] * K + kn + colOff, &bT[nxt][1 * 4096 + ldsw]);
#pragma unroll
    for (int ni = 0; ni < 4; ++ni)
#pragma unroll
      for (int kk = 0; kk < 2; ++kk)
        bb[ni][kk] = *(const bf16x8*)&bT[cur][(WC * 64 + ni * 16 + lrow) * 64 +
                                              ((kk * 4 + (lane >> 4)) ^ csw) * 8];
    PHASE_MFMA(0);
    __builtin_amdgcn_s_barrier();
    __builtin_amdgcn_sched_barrier(0);
    // ---- phase 1 ----
    gload16(Bt + (size_t)rowB[2] * K + kn + colOff, &bT[nxt][2 * 4096 + ldsw]);
    gload16(Bt + (size_t)rowB[3] * K + kn + colOff, &bT[nxt][3 * 4096 + ldsw]);
    PHASE_MFMA(1);
    asm volatile("s_waitcnt vmcnt(4)" ::: "memory");  // A1,A3(cur) landed
    __builtin_amdgcn_sched_barrier(0);
    __builtin_amdgcn_s_barrier();
    __builtin_amdgcn_sched_barrier(0);
    // ---- phase 2 ----
    gload16(A + (size_t)rowA[0] * K + kn + colOff, &aT[nxt][0 * 4096 + ldsw]);
    gload16(A + (size_t)rowA[2] * K + kn + colOff, &aT[nxt][2 * 4096 + ldsw]);
    PHASE_MFMA(2);
    __builtin_amdgcn_s_barrier();
    __builtin_amdgcn_sched_barrier(0);
    // ---- phase 3 ----
    gload16(A + (size_t)rowA[1] * K + kn + colOff, &aT[nxt][1 * 4096 + ldsw]);
    gload16(A + (size_t)rowA[3] * K + kn + colOff, &aT[nxt][3 * 4096 + ldsw]);
    PHASE_MFMA(3);
    asm volatile("s_waitcnt vmcnt(2)" ::: "memory");  // all but A1,A3(next) landed
    __builtin_amdgcn_sched_barrier(0);
    __builtin_amdgcn_s_barrier();
    __builtin_amdgcn_sched_barrier(0);
  }

  if constexpr (EPI == 6) {
    int nb = n0 + WC * 64;
    int gh = nb >> 6;
    float qse = (gh < 16) ? __expf(aux[gh]) : 1.0f;
    bool dn = gh < 32;
#pragma unroll
    for (int mi = 0; mi < 8; ++mi) {
#pragma unroll
      for (int r = 0; r < 4; ++r) {
        float vv[4]; float ss = 0.f;
#pragma unroll
        for (int ni = 0; ni < 4; ++ni) {
          vv[ni] = acc[mi][ni][r] + bias[nb + ni * 16 + lrow];
          ss += vv[ni] * vv[ni];
        }
        if (dn) {
          ss += __shfl_xor(ss, 1); ss += __shfl_xor(ss, 2);
          ss += __shfl_xor(ss, 4); ss += __shfl_xor(ss, 8);
          float rn = qse / fmaxf(sqrtf(ss), 1e-12f);
#pragma unroll
          for (int ni = 0; ni < 4; ++ni) vv[ni] *= rn;
        }
        int gm = m0 + WR * 128 + mi * 16 + (lane >> 4) * 4 + r;
        if (gm < M) {
#pragma unroll
          for (int ni = 0; ni < 4; ++ni)
            bfout[(size_t)gm * N + nb + ni * 16 + lrow] = f2bf(vv[ni]);
        }
      }
    }
  } else {
#pragma unroll
    for (int mi = 0; mi < 8; ++mi) {
#pragma unroll
      for (int ni = 0; ni < 4; ++ni) {
#pragma unroll
        for (int r = 0; r < 4; ++r) {
          int gm = m0 + WR * 128 + mi * 16 + (lane >> 4) * 4 + r;
          int gn = n0 + WC * 64 + ni * 16 + lrow;
          if (gm >= M || gn >= N) continue;
          bfout[(size_t)gm * N + gn] = f2bf(gelu_f(acc[mi][ni][r] + bias[gn]));
        }
      }
    }
  }
}

// ---------------- split-K combine (head) ----------------
__global__ __launch_bounds__(256) void k_comb_head(const float* __restrict__ p,
    const float* __restrict__ bias, float* __restrict__ out, int nsplit) {
  int row = blockIdx.x, t = threadIdx.x;
  const int N = 192;
  size_t stride = (size_t)2728 * N;
  if (t < 48) {
    int c = t * 4;
    float4 s = *(const float4*)&p[(size_t)row * N + c];
    for (int sp = 1; sp < nsplit; ++sp) {
      float4 qq = *(const float4*)&p[sp * stride + (size_t)row * N + c];
      s.x += qq.x; s.y += qq.y; s.z += qq.z; s.w += qq.w;
    }
    float4 bv = *(const float4*)&bias[c];
    s.x += bv.x; s.y += bv.y; s.z += bv.z; s.w += bv.w;
    *(float4*)&out[(size_t)row * N + c] = s;
  }
}

// ---------------- V transpose ----------------
__global__ __launch_bounds__(256) void k_vt(const ushort_t* __restrict__ qkv,
                                            ushort_t* __restrict__ vt) {
  int c = blockIdx.x, h = blockIdx.y, b = blockIdx.z;
  __shared__ ushort_t tile[64 * 72];
  int t = threadIdx.x;
#pragma unroll
  for (int i = 0; i < 2; ++i) {
    int vid = t + 256 * i;
    int row = vid >> 3, seg = (vid & 7) * 8;
    int l = c * 64 + row; if (l > 340) l = 340;
    uint4 v = *(const uint4*)&qkv[((size_t)(b * 341 + l)) * 3072 + 2048 + h * 64 + seg];
    *(uint4*)&tile[row * 72 + seg] = v;
  }
  __syncthreads();
  int d = t >> 2, lseg = (t & 3) * 16;
  ushort_t tmp[16];
#pragma unroll
  for (int j = 0; j < 16; ++j) tmp[j] = tile[(lseg + j) * 72 + d];
  size_t bh = (size_t)(b * 16 + h);
  ushort_t* dp = vt + (bh * 64 + d) * 384 + c * 64 + lseg;
  uint4 s0, s1;
  s0.x = (unsigned)tmp[0] | ((unsigned)tmp[1] << 16);
  s0.y = (unsigned)tmp[2] | ((unsigned)tmp[3] << 16);
  s0.z = (unsigned)tmp[4] | ((unsigned)tmp[5] << 16);
  s0.w = (unsigned)tmp[6] | ((unsigned)tmp[7] << 16);
  s1.x = (unsigned)tmp[8] | ((unsigned)tmp[9] << 16);
  s1.y = (unsigned)tmp[10] | ((unsigned)tmp[11] << 16);
  s1.z = (unsigned)tmp[12] | ((unsigned)tmp[13] << 16);
  s1.w = (unsigned)tmp[14] | ((unsigned)tmp[15] << 16);
  *(uint4*)dp = s0;
  *(uint4*)(dp + 8) = s1;
}

// ---------------- fused flash attention ----------------
__global__ __launch_bounds__(256) void k_attn(
    const ushort_t* __restrict__ qkv, const ushort_t* __restrict__ vtg,
    ushort_t* __restrict__ o) {
  int qt = blockIdx.x, h = blockIdx.y, b = blockIdx.z;
  int t = threadIdx.x, lane = t & 63, w = t >> 6;
  int q0 = qt * 64;
  size_t bh64 = (size_t)(b * 16 + h) * 64;
  __shared__ ushort_t qT[64 * 72], kT[64 * 72], vT[64 * 72];
  __shared__ ushort_t pT[4][16 * 72];
#pragma unroll
  for (int i = 0; i < 2; ++i) {
    int vid = t + 256 * i;
    int row = vid >> 3, seg = (vid & 7) * 8;
    int l = q0 + row; if (l > 340) l = 340;
    uint4 v = *(const uint4*)&qkv[((size_t)(b * 341 + l)) * 3072 + h * 64 + seg];
    *(uint4*)&qT[row * 72 + seg] = v;
  }
  int lrow = lane & 15, lk8 = (lane >> 4) * 8;
  int sq[4];
  float mrun[4], lsum[4];
  f32x4 accO[4];
#pragma unroll
  for (int r = 0; r < 4; ++r) {
    int lq = q0 + w * 16 + (lane >> 4) * 4 + r;
    sq[r] = sid_of(lq < 341 ? lq : 340);
    mrun[r] = -1e30f;
    lsum[r] = 0.f;
  }
#pragma unroll
  for (int d = 0; d < 4; ++d) accO[d] = (f32x4){0.f, 0.f, 0.f, 0.f};
  int nch = (qt == 0) ? 2 : 6;
  for (int c = 0; c < nch; ++c) {
    __syncthreads();
#pragma unroll
    for (int i = 0; i < 2; ++i) {
      int vid = t + 256 * i;
      int row = vid >> 3, seg = (vid & 7) * 8;
      int l = c * 64 + row; if (l > 340) l = 340;
      uint4 kv = *(const uint4*)&qkv[((size_t)(b * 341 + l)) * 3072 + 1024 + h * 64 + seg];
      *(uint4*)&kT[row * 72 + seg] = kv;
      uint4 vv = *(const uint4*)&vtg[(bh64 + row) * 384 + c * 64 + seg];
      *(uint4*)&vT[row * 72 + seg] = vv;
    }
    __syncthreads();
    f32x4 sf[4];
#pragma unroll
    for (int nf = 0; nf < 4; ++nf) sf[nf] = (f32x4){0.f, 0.f, 0.f, 0.f};
    __builtin_amdgcn_s_setprio(1);
#pragma unroll
    for (int ks = 0; ks < 2; ++ks) {
      bf16x8 aq = *(const bf16x8*)&qT[(w * 16 + lrow) * 72 + ks * 32 + lk8];
#pragma unroll
      for (int nf = 0; nf < 4; ++nf) {
        bf16x8 bk = *(const bf16x8*)&kT[(nf * 16 + lrow) * 72 + ks * 32 + lk8];
        sf[nf] = mfma16(aq, bk, sf[nf]);
      }
    }
    __builtin_amdgcn_s_setprio(0);
#pragma unroll
    for (int nf = 0; nf < 4; ++nf) {
      int lk = c * 64 + nf * 16 + lrow;
      int sk = lk < 341 ? sid_of(lk) : 9;
#pragma unroll
      for (int r = 0; r < 4; ++r)
        if (sk > sq[r]) sf[nf][r] = -1e30f;
    }
    float rs[4];
#pragma unroll
    for (int r = 0; r < 4; ++r) {
      float m = sf[0][r];
      m = fmaxf(m, sf[1][r]); m = fmaxf(m, sf[2][r]); m = fmaxf(m, sf[3][r]);
#pragma unroll
      for (int off = 1; off < 16; off <<= 1) m = fmaxf(m, __shfl_xor(m, off));
      if (m > mrun[r] + 8.0f) {
        float scl = __expf(mrun[r] - m);
        mrun[r] = m;
        lsum[r] *= scl;
#pragma unroll
        for (int d = 0; d < 4; ++d) accO[d][r] *= scl;
      }
      rs[r] = 0.f;
    }
    ushort_t* pw = &pT[w][0];
#pragma unroll
    for (int nf = 0; nf < 4; ++nf) {
#pragma unroll
      for (int r = 0; r < 4; ++r) {
        float p = __expf(sf[nf][r] - mrun[r]);
        rs[r] += p;
        pw[((lane >> 4) * 4 + r) * 72 + nf * 16 + lrow] = f2bf(p);
      }
    }
#pragma unroll
    for (int r = 0; r < 4; ++r) {
      float sum = rs[r];
#pragma unroll
      for (int off = 1; off < 16; off <<= 1) sum += __shfl_xor(sum, off);
      lsum[r] += sum;
    }
    __builtin_amdgcn_s_setprio(1);
#pragma unroll
    for (int ks = 0; ks < 2; ++ks) {
      bf16x8 ap = *(const bf16x8*)&pw[lrow * 72 + ks * 32 + lk8];
#pragma unroll
      for (int d = 0; d < 4; ++d) {
        bf16x8 bv = *(const bf16x8*)&vT[(d * 16 + lrow) * 72 + ks * 32 + lk8];
        accO[d] = mfma16(ap, bv, accO[d]);
      }
    }
    __builtin_amdgcn_s_setprio(0);
  }
#pragma unroll
  for (int d = 0; d < 4; ++d) {
#pragma unroll
    for (int r = 0; r < 4; ++r) {
      int lq = q0 + w * 16 + (lane >> 4) * 4 + r;
      if (lq < 341) {
        float ov = accO[d][r] / fmaxf(lsum[r], 1e-30f);
        o[((size_t)(b * 341 + lq)) * 1024 + h * 64 + d * 16 + lrow] = f2bf(ov);
      }
    }
  }
}

// ---------------- launcher ----------------
extern "C" void kernel_launch(void* const* d_in, const int* in_sizes, int n_in,
                              void* d_out, int out_size, void* d_ws, size_t ws_size,
                              hipStream_t stream) {
  const float* patches   = (const float*)d_in[0];
  const int*   labels    = (const int*)d_in[1];
  const float* W_patch   = (const float*)d_in[2];
  const float* b_patch   = (const float*)d_in[3];
  const float* pos       = (const float*)d_in[4];
  const float* scale_emb = (const float*)d_in[5];
  const float* class_emb = (const float*)d_in[6];
  const float* ada_W     = (const float*)d_in[7];
  const float* ada_b     = (const float*)d_in[8];
  const float* qkv_W     = (const float*)d_in[9];
  const float* qkv_b     = (const float*)d_in[10];
  const float* q_scale   = (const float*)d_in[11];
  const float* proj_W    = (const float*)d_in[12];
  const float* proj_b    = (const float*)d_in[13];
  const float* fc1_W     = (const float*)d_in[14];
  const float* fc1_b     = (const float*)d_in[15];
  const float* fc2_W     = (const float*)d_in[16];
  const float* fc2_b     = (const float*)d_in[17];
  const float* hada_W    = (const float*)d_in[18];
  const float* hada_b    = (const float*)d_in[19];
  const float* head_W    = (const float*)d_in[20];
  const float* head_b    = (const float*)d_in[21];
  (void)in_sizes; (void)n_in; (void)out_size; (void)ws_size;

  char* wsb = (char*)d_ws;
  size_t off = 0;
  auto alloc = [&](size_t bytes) -> void* {
    void* p = wsb + off;
    off = (off + bytes + 255) & ~(size_t)255;
    return p;
  };

  float*    f_cond   = (float*)alloc(8 * 1024 * 4);
  float*    f_ada    = (float*)alloc((size_t)8 * 8 * 6144 * 4);
  float*    f_hada   = (float*)alloc(8 * 2048 * 4);
  float*    f_x      = (float*)alloc((size_t)2728 * 1024 * 4);
  ushort_t* u_h      = (ushort_t*)alloc((size_t)2728 * 1024 * 2);
  ushort_t* u_qkv    = (ushort_t*)alloc((size_t)2728 * 3072 * 2);
  ushort_t* u_vt     = (ushort_t*)alloc((size_t)128 * 64 * 384 * 2);
  ushort_t* u_o      = (ushort_t*)alloc((size_t)2728 * 1024 * 2);
  ushort_t* u_mid    = (ushort_t*)alloc((size_t)2728 * 4096 * 2);
  float*    f_part   = (float*)alloc((size_t)2 * 2728 * 1024 * 4);
  ushort_t* u_patch  = (ushort_t*)alloc((size_t)2720 * 192 * 2);
  ushort_t* u_qkvt   = (ushort_t*)alloc((size_t)8 * 3072 * 1024 * 2);
  ushort_t* u_projt  = (ushort_t*)alloc((size_t)8 * 1024 * 1024 * 2);
  ushort_t* u_fc1t   = (ushort_t*)alloc((size_t)8 * 4096 * 1024 * 2);
  ushort_t* u_fc2t   = (ushort_t*)alloc((size_t)8 * 1024 * 4096 * 2);
  ushort_t* u_wpt    = (ushort_t*)alloc((size_t)1024 * 192 * 2);
  ushort_t* u_wht    = (ushort_t*)alloc((size_t)192 * 1024 * 2);

  const int MT = 22;   // ceil(2728/128)
  const int MT64 = 43; // ceil(2728/64)
  const int MT256 = 11; // ceil(2728/256)

  k_cond_x0<<<8, 256, 0, stream>>>(labels, class_emb, pos, scale_emb, f_cond, f_x);
  k_transpose<<<dim3(32, 6, 1), 256, 0, stream>>>(W_patch, u_wpt, 192, 1024);
  k_transpose<<<dim3(6, 32, 1), 256, 0, stream>>>(head_W, u_wht, 1024, 192);
  k_convert<<<510, 256, 0, stream>>>(patches, u_patch, 130560);
  k_ada<<<dim3(96, 9), 256, 0, stream>>>(f_cond, ada_W, ada_b, hada_W, hada_b, f_ada, f_hada);
  k_transpose<<<dim3(96, 32, 8), 256, 0, stream>>>(qkv_W, u_qkvt, 1024, 3072);
  k_transpose<<<dim3(32, 32, 8), 256, 0, stream>>>(proj_W, u_projt, 1024, 1024);
  k_transpose<<<dim3(128, 32, 8), 256, 0, stream>>>(fc1_W, u_fc1t, 1024, 4096);
  k_transpose<<<dim3(32, 128, 8), 256, 0, stream>>>(fc2_W, u_fc2t, 4096, 1024);

  k_gemm<4, 128><<<dim3(8, MT), 256, 0, stream>>>(u_patch, u_wpt, b_patch, nullptr, nullptr,
                                                  nullptr, f_x, pos, scale_emb, 2720, 1024, 192, 192);
  // layer 0 LN1
  k_ln<<<2728, 256, 0, stream>>>(f_x, u_h, f_ada, 6144, 2048, 4096);

  for (int i = 0; i < 8; ++i) {
    const float* adaL = f_ada + (size_t)i * 8 * 6144;
    // qkv: 256x256 8-phase + fused qk-norm
    k_gemm8<6><<<dim3(12, MT256), 512, 0, stream>>>(u_h, u_qkvt + (size_t)i * 3072 * 1024,
                                                    qkv_b + (size_t)i * 3072, u_qkv,
                                                    q_scale + (size_t)i * 16, 2728, 3072, 1024);
    k_vt<<<dim3(6, 16, 8), 256, 0, stream>>>(u_qkv, u_vt);
    k_attn<<<dim3(6, 16, 8), 256, 0, stream>>>(u_qkv, u_vt, u_o);
    k_gemm<1, 64><<<dim3(8, MT64, 1), 256, 0, stream>>>(u_o, u_projt + (size_t)i * 1024 * 1024,
                                                        proj_b + (size_t)i * 1024, nullptr,
                                                        nullptr, adaL, f_x, nullptr, nullptr,
                                                        2728, 1024, 1024, 1024);
    k_ln<<<2728, 256, 0, stream>>>(f_x, u_h, adaL, 6144, 3072, 5120);
    // fc1: 256x256 8-phase + gelu
    k_gemm8<2><<<dim3(16, MT256), 512, 0, stream>>>(u_h, u_fc1t + (size_t)i * 4096 * 1024,
                                                    fc1_b + (size_t)i * 4096, u_mid,
                                                    nullptr, 2728, 4096, 1024);
    k_gemm<7, 64><<<dim3(8, MT64, 2), 256, 0, stream>>>(u_mid, u_fc2t + (size_t)i * 4096 * 1024,
                                                        nullptr, f_part, nullptr, nullptr,
                                                        nullptr, nullptr, nullptr,
                                                        2728, 1024, 4096, 2048);
    if (i < 7) {
      k_comb_ln<<<2728, 256, 0, stream>>>(f_part, fc2_b + (size_t)i * 1024, adaL, 1024,
                                          f_x, f_ada + (size_t)(i + 1) * 8 * 6144,
                                          6144, 2048, 4096, u_h);
    } else {
      k_comb_ln<<<2728, 256, 0, stream>>>(f_part, fc2_b + (size_t)i * 1024, adaL, 1024,
                                          f_x, f_hada, 2048, 0, 1024, u_h);
    }
  }

  k_gemm<7, 64><<<dim3(2, MT64, 4), 256, 0, stream>>>(u_h, u_wht, nullptr, f_part, nullptr,
                                                      nullptr, nullptr, nullptr, nullptr,
                                                      2728, 192, 1024, 256);
  k_comb_head<<<2728, 256, 0, stream>>>(f_part, head_b, (float*)d_out, 4);
}

// Round 12
// 1767.063 us; speedup vs baseline: 1.0763x; 1.0763x over previous
//
#include <hip/hip_runtime.h>

typedef unsigned short ushort_t;
typedef __bf16 bf16x8 __attribute__((ext_vector_type(8)));
typedef float f32x4 __attribute__((ext_vector_type(4)));

#define DEV __device__ __forceinline__

DEV ushort_t f2bf(float x) {
  union { float f; unsigned u; } v; v.f = x;
  unsigned r = v.u + 0x7FFFu + ((v.u >> 16) & 1u);
  return (ushort_t)(r >> 16);
}
DEV float bf2f(ushort_t h) {
  union { unsigned u; float f; } v; v.u = (unsigned)h << 16;
  return v.f;
}
DEV int sid_of(int l) { return l < 5 ? 0 : (l < 21 ? 1 : (l < 85 ? 2 : 3)); }
DEV float fast_tanh(float u) { return 1.0f - 2.0f / (__expf(2.0f * u) + 1.0f); }
DEV float gelu_f(float x) {
  float u = 0.7978845608028654f * (x + 0.044715f * x * x * x);
  return 0.5f * x * (1.0f + fast_tanh(u));
}
DEV float silu_f(float x) { return x / (1.0f + __expf(-x)); }
DEV f32x4 mfma16(bf16x8 a, bf16x8 b, f32x4 c) {
  return __builtin_amdgcn_mfma_f32_16x16x32_bf16(a, b, c, 0, 0, 0);
}
DEV void gload16(const void* src, void* dst) {
  __builtin_amdgcn_global_load_lds(
      (const __attribute__((address_space(1))) void*)(uintptr_t)src,
      (__attribute__((address_space(3))) void*)(uintptr_t)dst, 16, 0, 0);
}

// ---------------- cond gather + x row 0 ----------------
__global__ __launch_bounds__(256) void k_cond_x0(
    const int* __restrict__ labels, const float* __restrict__ class_emb,
    const float* __restrict__ pos, const float* __restrict__ semb,
    float* __restrict__ cond, float* __restrict__ x) {
  int b = blockIdx.x, t = threadIdx.x;
  int lab = labels[b];
  float4 cv = *(const float4*)&class_emb[(size_t)lab * 1024 + t * 4];
  *(float4*)&cond[(size_t)b * 1024 + t * 4] = cv;
  float4 pv = *(const float4*)&pos[t * 4];
  float4 sv = *(const float4*)&semb[t * 4];
  float4 xv;
  xv.x = cv.x + pv.x + sv.x; xv.y = cv.y + pv.y + sv.y;
  xv.z = cv.z + pv.z + sv.z; xv.w = cv.w + pv.w + sv.w;
  *(float4*)&x[(size_t)b * 341 * 1024 + t * 4] = xv;
}

// ---------------- f32 -> bf16 convert ----------------
__global__ __launch_bounds__(256) void k_convert(const float* __restrict__ src,
                                                 ushort_t* __restrict__ dst, int n4) {
  int i = blockIdx.x * 256 + threadIdx.x;
  if (i < n4) {
    float4 v = *(const float4*)&src[(size_t)i * 4];
    uint2 pk;
    pk.x = (unsigned)f2bf(v.x) | ((unsigned)f2bf(v.y) << 16);
    pk.y = (unsigned)f2bf(v.z) | ((unsigned)f2bf(v.w) << 16);
    *(uint2*)&dst[(size_t)i * 4] = pk;
  }
}

// ---------------- transpose f32 [K][N] -> bf16 [N][K], batched over z ----------------
__global__ __launch_bounds__(256) void k_transpose(const float* __restrict__ src,
                                                   ushort_t* __restrict__ dst, int K, int N) {
  __shared__ ushort_t tile[32][33];
  int z = blockIdx.z;
  src += (size_t)z * K * N;
  dst += (size_t)z * K * N;
  int k0 = blockIdx.y * 32, n0 = blockIdx.x * 32;
  int t = threadIdx.x;
  int r = t >> 3, c = (t & 7) * 4;
  float4 v = *(const float4*)&src[(size_t)(k0 + r) * N + n0 + c];
  tile[r][c] = f2bf(v.x); tile[r][c + 1] = f2bf(v.y);
  tile[r][c + 2] = f2bf(v.z); tile[r][c + 3] = f2bf(v.w);
  __syncthreads();
  ushort_t o0 = tile[c][r], o1 = tile[c + 1][r], o2 = tile[c + 2][r], o3 = tile[c + 3][r];
  uint2 pk;
  pk.x = (unsigned)o0 | ((unsigned)o1 << 16);
  pk.y = (unsigned)o2 | ((unsigned)o3 << 16);
  *(uint2*)&dst[(size_t)(n0 + r) * K + k0 + c] = pk;
}

// ---------------- adaLN GEMM ----------------
__global__ __launch_bounds__(256) void k_ada(const float* __restrict__ cond,
    const float* __restrict__ ada_W, const float* __restrict__ ada_b,
    const float* __restrict__ hada_W, const float* __restrict__ hada_b,
    float* __restrict__ ada_out, float* __restrict__ hada_out) {
  int gy = blockIdx.y;
  bool head = (gy == 8);
  int Nw = head ? 2048 : 6144;
  int n0 = blockIdx.x * 64;
  if (n0 >= Nw) return;
  __shared__ float sc[8 * 1024];
  __shared__ float red[4][64][8];
  int t = threadIdx.x;
  for (int i = t; i < 2048; i += 256) {
    float4 cv = *(const float4*)&cond[(size_t)i * 4];
    float* d = &sc[i * 4];
    d[0] = silu_f(cv.x); d[1] = silu_f(cv.y); d[2] = silu_f(cv.z); d[3] = silu_f(cv.w);
  }
  __syncthreads();
  const float* W = head ? hada_W : ada_W + (size_t)gy * 1024 * 6144;
  const float* bs = head ? hada_b : ada_b + (size_t)gy * 6144;
  float* op = head ? hada_out : ada_out + (size_t)gy * 8 * 6144;
  int col = n0 + (t & 63), kq = t >> 6;
  float acc[8] = {0.f, 0.f, 0.f, 0.f, 0.f, 0.f, 0.f, 0.f};
  for (int k = kq * 256; k < kq * 256 + 256; ++k) {
    float wv = W[(size_t)k * Nw + col];
#pragma unroll
    for (int b2 = 0; b2 < 8; ++b2) acc[b2] += wv * sc[b2 * 1024 + k];
  }
#pragma unroll
  for (int b2 = 0; b2 < 8; ++b2) red[kq][t & 63][b2] = acc[b2];
  __syncthreads();
  if (t < 64) {
    int colc = n0 + t;
    float bias = bs[colc];
#pragma unroll
    for (int b2 = 0; b2 < 8; ++b2) {
      float v = red[0][t][b2] + red[1][t][b2] + red[2][t][b2] + red[3][t][b2] + bias;
      op[(size_t)b2 * Nw + colc] = v;
    }
  }
}

// ---------------- LN + modulate -> bf16 ----------------
__global__ __launch_bounds__(256) void k_ln(const float* __restrict__ x,
    ushort_t* __restrict__ hout, const float* __restrict__ ada,
    int stride, int soff, int shoff) {
  int row = blockIdx.x, t = threadIdx.x;
  int b = row / 341;
  const float* xr = x + (size_t)row * 1024;
  float4 xv = *(const float4*)&xr[t * 4];
  float s = xv.x + xv.y + xv.z + xv.w;
  float ss = xv.x * xv.x + xv.y * xv.y + xv.z * xv.z + xv.w * xv.w;
#pragma unroll
  for (int off = 1; off < 64; off <<= 1) { s += __shfl_xor(s, off); ss += __shfl_xor(ss, off); }
  __shared__ float red[8];
  int w = t >> 6, lane = t & 63;
  if (lane == 0) { red[w] = s; red[w + 4] = ss; }
  __syncthreads();
  s = red[0] + red[1] + red[2] + red[3];
  ss = red[4] + red[5] + red[6] + red[7];
  float mean = s * (1.f / 1024.f);
  float var = ss * (1.f / 1024.f) - mean * mean;
  float rstd = rsqrtf(var + 1e-6f);
  const float* ar = ada + (size_t)b * stride;
  float xe[4] = {xv.x, xv.y, xv.z, xv.w};
  ushort_t tmp[4];
#pragma unroll
  for (int j = 0; j < 4; ++j) {
    int n = t * 4 + j;
    float val = (xe[j] - mean) * rstd * (1.f + ar[soff + n]) + ar[shoff + n];
    tmp[j] = f2bf(val);
  }
  uint2 pk;
  pk.x = (unsigned)tmp[0] | ((unsigned)tmp[1] << 16);
  pk.y = (unsigned)tmp[2] | ((unsigned)tmp[3] << 16);
  *(uint2*)&hout[(size_t)row * 1024 + t * 4] = pk;
}

// ---------------- fused residual-combine + LN + modulate (fc2 tail, bf16 partials) ----------------
__global__ __launch_bounds__(256) void k_comb_ln(
    const ushort_t* __restrict__ p, const float* __restrict__ bias,
    const float* __restrict__ adag, int goff,
    float* __restrict__ x, const float* __restrict__ adaln,
    int lnstride, int soff, int shoff,
    ushort_t* __restrict__ hout) {
  int row = blockIdx.x, t = threadIdx.x;
  int b = row / 341;
  int c = t * 4;
  const ushort_t* pr = p + (size_t)row * 1024 + c;
  uint2 a0 = *(const uint2*)pr;
  uint2 a1 = *(const uint2*)(pr + (size_t)2728 * 1024);
  float s0 = bf2f((ushort_t)a0.x) + bf2f((ushort_t)a1.x);
  float s1 = bf2f((ushort_t)(a0.x >> 16)) + bf2f((ushort_t)(a1.x >> 16));
  float s2 = bf2f((ushort_t)a0.y) + bf2f((ushort_t)a1.y);
  float s3 = bf2f((ushort_t)(a0.y >> 16)) + bf2f((ushort_t)(a1.y >> 16));
  float4 bv = *(const float4*)&bias[c];
  const float* gr = adag + (size_t)b * 6144 + goff + c;
  float4 xv = *(float4*)&x[(size_t)row * 1024 + c];
  xv.x += gr[0] * (s0 + bv.x);
  xv.y += gr[1] * (s1 + bv.y);
  xv.z += gr[2] * (s2 + bv.z);
  xv.w += gr[3] * (s3 + bv.w);
  *(float4*)&x[(size_t)row * 1024 + c] = xv;
  float sm = xv.x + xv.y + xv.z + xv.w;
  float ss = xv.x * xv.x + xv.y * xv.y + xv.z * xv.z + xv.w * xv.w;
#pragma unroll
  for (int off = 1; off < 64; off <<= 1) { sm += __shfl_xor(sm, off); ss += __shfl_xor(ss, off); }
  __shared__ float red[8];
  int w = t >> 6, lane = t & 63;
  if (lane == 0) { red[w] = sm; red[w + 4] = ss; }
  __syncthreads();
  sm = red[0] + red[1] + red[2] + red[3];
  ss = red[4] + red[5] + red[6] + red[7];
  float mean = sm * (1.f / 1024.f);
  float var = ss * (1.f / 1024.f) - mean * mean;
  float rstd = rsqrtf(var + 1e-6f);
  const float* ar = adaln + (size_t)b * lnstride;
  float xe[4] = {xv.x, xv.y, xv.z, xv.w};
  ushort_t tmp[4];
#pragma unroll
  for (int j = 0; j < 4; ++j) {
    int n = c + j;
    float val = (xe[j] - mean) * rstd * (1.f + ar[soff + n]) + ar[shoff + n];
    tmp[j] = f2bf(val);
  }
  uint2 pk;
  pk.x = (unsigned)tmp[0] | ((unsigned)tmp[1] << 16);
  pk.y = (unsigned)tmp[2] | ((unsigned)tmp[3] << 16);
  *(uint2*)&hout[(size_t)row * 1024 + c] = pk;
}

// ---------------- main GEMM: 3-buffer / 1-barrier-per-K-step (R9, proven) ----------------
// EPI 1: xres += aux*v   EPI 2: bfout=gelu(v)  EPI 4: patch-embed
// EPI 6: qkv+qknorm      EPI 7: f32 partial    EPI 8: bf16 partial
template <int EPI, int BM>
__global__ __launch_bounds__(256, 3) void k_gemm(
    const ushort_t* __restrict__ A, const ushort_t* __restrict__ Bt,
    const float* __restrict__ bias, float* __restrict__ fout,
    ushort_t* __restrict__ bfout, const float* __restrict__ aux,
    float* __restrict__ xres, const float* __restrict__ pos,
    const float* __restrict__ semb, int M, int N, int K, int KS) {
  constexpr int NI = (BM == 128) ? 4 : 2;
  constexpr int WNB = (BM == 128) ? 64 : 32;
  __shared__ ushort_t aT[3][BM * 32];
  __shared__ ushort_t bT[3][128 * 32];
  int tid = threadIdx.x;
  int lane = tid & 63, w = tid >> 6;
  int WR = (BM == 128) ? (w >> 1) : 0;
  int WC = (BM == 128) ? (w & 1) : w;

  int gx = gridDim.x;
  int nwg = gx * gridDim.y;
  int orig = blockIdx.y * gx + blockIdx.x;
  int q = nwg >> 3, r8 = nwg & 7;
  int xcd = orig & 7, idx = orig >> 3;
  int lin = (xcd < r8 ? xcd * (q + 1) : r8 * (q + 1) + (xcd - r8) * q) + idx;
  int bx = lin % gx, by = lin / gx;

  int m0 = by * BM, n0 = bx * 128;
  int kbase = blockIdx.z * KS;
  f32x4 acc[4][NI];
#pragma unroll
  for (int i = 0; i < 4; ++i)
#pragma unroll
    for (int j = 0; j < NI; ++j) acc[i][j] = (f32x4){0.f, 0.f, 0.f, 0.f};

  int lrow = lane & 15;
  int csw = (lrow >> 1) & 3;
  int coff = ((lane >> 4) ^ csw) * 8;

  int s_row0 = tid >> 2, s_u = tid & 3;
  int s_c = s_u ^ ((s_row0 >> 1) & 3);
  int aR0 = m0 + s_row0; if (aR0 > M - 1) aR0 = M - 1;
  int bR0 = n0 + s_row0; if (bR0 > N - 1) bR0 = N - 1;
  int aR1 = m0 + s_row0 + 64; if (aR1 > M - 1) aR1 = M - 1;
  int bR1 = n0 + s_row0 + 64; if (bR1 > N - 1) bR1 = N - 1;
  const ushort_t* aSrc0 = A + (size_t)aR0 * K + kbase + s_c * 8;
  const ushort_t* aSrc1 = A + (size_t)aR1 * K + kbase + s_c * 8;
  const ushort_t* bSrc0 = Bt + (size_t)bR0 * K + kbase + s_c * 8;
  const ushort_t* bSrc1 = Bt + (size_t)bR1 * K + kbase + s_c * 8;
  int slot0 = w * 512, slot1 = 2048 + w * 512;

  int nsteps = KS >> 5;
  auto STAGE = [&](int k0, int buf) {
    gload16(aSrc0 + k0, &aT[buf][slot0]);
    if constexpr (BM == 128) gload16(aSrc1 + k0, &aT[buf][slot1]);
    gload16(bSrc0 + k0, &bT[buf][slot0]);
    gload16(bSrc1 + k0, &bT[buf][slot1]);
  };

  STAGE(0, 0);
  int cur = 0;
  for (int s = 0; s < nsteps; ++s) {
    int nb = cur + 1; if (nb == 3) nb = 0;
    int kn = (s + 1 < nsteps) ? ((s + 1) << 5) : 0;  // wrap keeps vmcnt uniform
    STAGE(kn, nb);
    if constexpr (BM == 128)
      asm volatile("s_waitcnt vmcnt(4)" ::: "memory");
    else
      asm volatile("s_waitcnt vmcnt(3)" ::: "memory");
    __builtin_amdgcn_sched_barrier(0);
    __builtin_amdgcn_s_barrier();
    __builtin_amdgcn_sched_barrier(0);
    bf16x8 af[4], bb[NI];
#pragma unroll
    for (int mi = 0; mi < 4; ++mi)
      af[mi] = *(const bf16x8*)&aT[cur][(WR * 64 + mi * 16 + lrow) * 32 + coff];
#pragma unroll
    for (int ni = 0; ni < NI; ++ni)
      bb[ni] = *(const bf16x8*)&bT[cur][(WC * WNB + ni * 16 + lrow) * 32 + coff];
#pragma unroll
    for (int mi = 0; mi < 4; ++mi)
#pragma unroll
      for (int ni = 0; ni < NI; ++ni)
        acc[mi][ni] = mfma16(af[mi], bb[ni], acc[mi][ni]);
    cur = nb;  // 3-buffer rotation provides WAR safety
  }

  if constexpr (EPI == 6) {
    int nb = n0 + WC * 64;
    int gh = nb >> 6;
    float qse = (gh < 16) ? __expf(aux[gh]) : 1.0f;
    bool dn = gh < 32;
#pragma unroll
    for (int mi = 0; mi < 4; ++mi) {
#pragma unroll
      for (int r = 0; r < 4; ++r) {
        float vv[4]; float ss = 0.f;
#pragma unroll
        for (int ni = 0; ni < 4; ++ni) {
          vv[ni] = acc[mi][ni][r] + bias[nb + ni * 16 + lrow];
          ss += vv[ni] * vv[ni];
        }
        if (dn) {
          ss += __shfl_xor(ss, 1); ss += __shfl_xor(ss, 2);
          ss += __shfl_xor(ss, 4); ss += __shfl_xor(ss, 8);
          float rn = qse / fmaxf(sqrtf(ss), 1e-12f);
#pragma unroll
          for (int ni = 0; ni < 4; ++ni) vv[ni] *= rn;
        }
        int gm = m0 + WR * 64 + mi * 16 + (lane >> 4) * 4 + r;
        if (gm < M) {
#pragma unroll
          for (int ni = 0; ni < 4; ++ni)
            bfout[(size_t)gm * N + nb + ni * 16 + lrow] = f2bf(vv[ni]);
        }
      }
    }
  } else if constexpr (EPI == 1) {
#pragma unroll
    for (int mi = 0; mi < 4; ++mi) {
#pragma unroll
      for (int r = 0; r < 4; ++r) {
        int gm = m0 + WR * 64 + mi * 16 + (lane >> 4) * 4 + r;
        if (gm >= M) continue;
        int b = gm / 341;                 // hoisted: one division per row
        size_t xb = (size_t)gm * 1024;
        const float* ax = aux + (size_t)b * 6144;
#pragma unroll
        for (int ni = 0; ni < NI; ++ni) {
          int gn = n0 + WC * WNB + ni * 16 + lrow;
          if (gn >= N) continue;
          xres[xb + gn] += ax[gn] * (acc[mi][ni][r] + bias[gn]);
        }
      }
    }
  } else {
#pragma unroll
    for (int mi = 0; mi < 4; ++mi) {
#pragma unroll
      for (int ni = 0; ni < NI; ++ni) {
#pragma unroll
        for (int r = 0; r < 4; ++r) {
          int gm = m0 + WR * 64 + mi * 16 + (lane >> 4) * 4 + r;
          int gn = n0 + WC * WNB + ni * 16 + lrow;
          if (gm >= M || gn >= N) continue;
          if constexpr (EPI == 7) {
            fout[(size_t)blockIdx.z * M * N + (size_t)gm * N + gn] = acc[mi][ni][r];
          } else if constexpr (EPI == 8) {
            bfout[(size_t)blockIdx.z * M * N + (size_t)gm * N + gn] = f2bf(acc[mi][ni][r]);
          } else {
            float v = acc[mi][ni][r] + bias[gn];
            if constexpr (EPI == 2) {
              bfout[(size_t)gm * N + gn] = f2bf(gelu_f(v));
            } else if constexpr (EPI == 4) {
              int b = gm / 340, l = gm % 340 + 1;
              float val = v + pos[(size_t)l * 1024 + gn] + semb[(size_t)sid_of(l) * 1024 + gn];
              xres[((size_t)(b * 341 + l)) * 1024 + gn] = val;
            }
          }
        }
      }
    }
  }
}

// ---------------- split-K combine (head) ----------------
__global__ __launch_bounds__(256) void k_comb_head(const float* __restrict__ p,
    const float* __restrict__ bias, float* __restrict__ out, int nsplit) {
  int row = blockIdx.x, t = threadIdx.x;
  const int N = 192;
  size_t stride = (size_t)2728 * N;
  if (t < 48) {
    int c = t * 4;
    float4 s = *(const float4*)&p[(size_t)row * N + c];
    for (int sp = 1; sp < nsplit; ++sp) {
      float4 qq = *(const float4*)&p[sp * stride + (size_t)row * N + c];
      s.x += qq.x; s.y += qq.y; s.z += qq.z; s.w += qq.w;
    }
    float4 bv = *(const float4*)&bias[c];
    s.x += bv.x; s.y += bv.y; s.z += bv.z; s.w += bv.w;
    *(float4*)&out[(size_t)row * N + c] = s;
  }
}

// ---------------- fused flash attention (in-LDS V gather, defer-max) ----------------
__global__ __launch_bounds__(256) void k_attn(
    const ushort_t* __restrict__ qkv, ushort_t* __restrict__ o) {
  int qt = blockIdx.x, h = blockIdx.y, b = blockIdx.z;
  int t = threadIdx.x, lane = t & 63, w = t >> 6;
  int q0 = qt * 64;
  __shared__ ushort_t qT[64 * 72], kT[64 * 72], vS[64 * 72], vT[64 * 72];
  __shared__ ushort_t pT[4][16 * 72];
#pragma unroll
  for (int i = 0; i < 2; ++i) {
    int vid = t + 256 * i;
    int row = vid >> 3, seg = (vid & 7) * 8;
    int l = q0 + row; if (l > 340) l = 340;
    uint4 v = *(const uint4*)&qkv[((size_t)(b * 341 + l)) * 3072 + h * 64 + seg];
    *(uint4*)&qT[row * 72 + seg] = v;
  }
  int lrow = lane & 15, lk8 = (lane >> 4) * 8;
  int sq[4];
  float mrun[4], lsum[4];
  f32x4 accO[4];
#pragma unroll
  for (int r = 0; r < 4; ++r) {
    int lq = q0 + w * 16 + (lane >> 4) * 4 + r;
    sq[r] = sid_of(lq < 341 ? lq : 340);
    mrun[r] = -1e30f;
    lsum[r] = 0.f;
  }
#pragma unroll
  for (int d = 0; d < 4; ++d) accO[d] = (f32x4){0.f, 0.f, 0.f, 0.f};
  int nch = (qt == 0) ? 2 : 6;
  int vd = t >> 2, vlseg = (t & 3) * 16;
  for (int c = 0; c < nch; ++c) {
    __syncthreads();
#pragma unroll
    for (int i = 0; i < 2; ++i) {
      int vid = t + 256 * i;
      int row = vid >> 3, seg = (vid & 7) * 8;
      int l = c * 64 + row; if (l > 340) l = 340;
      size_t base = ((size_t)(b * 341 + l)) * 3072 + h * 64 + seg;
      uint4 kv = *(const uint4*)&qkv[base + 1024];
      uint4 vv = *(const uint4*)&qkv[base + 2048];
      *(uint4*)&kT[row * 72 + seg] = kv;
      *(uint4*)&vS[row * 72 + seg] = vv;
    }
    __syncthreads();
    ushort_t tmp[16];
#pragma unroll
    for (int j = 0; j < 16; ++j) tmp[j] = vS[(vlseg + j) * 72 + vd];
    f32x4 sf[4];
#pragma unroll
    for (int nf = 0; nf < 4; ++nf) sf[nf] = (f32x4){0.f, 0.f, 0.f, 0.f};
    __builtin_amdgcn_s_setprio(1);
#pragma unroll
    for (int ks = 0; ks < 2; ++ks) {
      bf16x8 aq = *(const bf16x8*)&qT[(w * 16 + lrow) * 72 + ks * 32 + lk8];
#pragma unroll
      for (int nf = 0; nf < 4; ++nf) {
        bf16x8 bk = *(const bf16x8*)&kT[(nf * 16 + lrow) * 72 + ks * 32 + lk8];
        sf[nf] = mfma16(aq, bk, sf[nf]);
      }
    }
    __builtin_amdgcn_s_setprio(0);
#pragma unroll
    for (int nf = 0; nf < 4; ++nf) {
      int lk = c * 64 + nf * 16 + lrow;
      int sk = lk < 341 ? sid_of(lk) : 9;
#pragma unroll
      for (int r = 0; r < 4; ++r)
        if (sk > sq[r]) sf[nf][r] = -1e30f;
    }
    float rs[4];
#pragma unroll
    for (int r = 0; r < 4; ++r) {
      float m = sf[0][r];
      m = fmaxf(m, sf[1][r]); m = fmaxf(m, sf[2][r]); m = fmaxf(m, sf[3][r]);
#pragma unroll
      for (int off = 1; off < 16; off <<= 1) m = fmaxf(m, __shfl_xor(m, off));
      // T13 defer-max: rescale only when chunk max exceeds running max + 8
      if (m > mrun[r] + 8.0f) {
        float scl = __expf(mrun[r] - m);
        mrun[r] = m;
        lsum[r] *= scl;
#pragma unroll
        for (int d = 0; d < 4; ++d) accO[d][r] *= scl;
      }
      rs[r] = 0.f;
    }
    ushort_t* pw = &pT[w][0];
#pragma unroll
    for (int nf = 0; nf < 4; ++nf) {
#pragma unroll
      for (int r = 0; r < 4; ++r) {
        float p = __expf(sf[nf][r] - mrun[r]);
        rs[r] += p;
        pw[((lane >> 4) * 4 + r) * 72 + nf * 16 + lrow] = f2bf(p);
      }
    }
#pragma unroll
    for (int r = 0; r < 4; ++r) {
      float sum = rs[r];
#pragma unroll
      for (int off = 1; off < 16; off <<= 1) sum += __shfl_xor(sum, off);
      lsum[r] += sum;
    }
    {
      uint4 s0, s1;
      s0.x = (unsigned)tmp[0] | ((unsigned)tmp[1] << 16);
      s0.y = (unsigned)tmp[2] | ((unsigned)tmp[3] << 16);
      s0.z = (unsigned)tmp[4] | ((unsigned)tmp[5] << 16);
      s0.w = (unsigned)tmp[6] | ((unsigned)tmp[7] << 16);
      s1.x = (unsigned)tmp[8] | ((unsigned)tmp[9] << 16);
      s1.y = (unsigned)tmp[10] | ((unsigned)tmp[11] << 16);
      s1.z = (unsigned)tmp[12] | ((unsigned)tmp[13] << 16);
      s1.w = (unsigned)tmp[14] | ((unsigned)tmp[15] << 16);
      *(uint4*)&vT[vd * 72 + vlseg] = s0;
      *(uint4*)&vT[vd * 72 + vlseg + 8] = s1;
    }
    __syncthreads();
    __builtin_amdgcn_s_setprio(1);
#pragma unroll
    for (int ks = 0; ks < 2; ++ks) {
      bf16x8 ap = *(const bf16x8*)&pw[lrow * 72 + ks * 32 + lk8];
#pragma unroll
      for (int d = 0; d < 4; ++d) {
        bf16x8 bv = *(const bf16x8*)&vT[(d * 16 + lrow) * 72 + ks * 32 + lk8];
        accO[d] = mfma16(ap, bv, accO[d]);
      }
    }
    __builtin_amdgcn_s_setprio(0);
  }
#pragma unroll
  for (int d = 0; d < 4; ++d) {
#pragma unroll
    for (int r = 0; r < 4; ++r) {
      int lq = q0 + w * 16 + (lane >> 4) * 4 + r;
      if (lq < 341) {
        float ov = accO[d][r] / fmaxf(lsum[r], 1e-30f);
        o[((size_t)(b * 341 + lq)) * 1024 + h * 64 + d * 16 + lrow] = f2bf(ov);
      }
    }
  }
}

// ---------------- launcher ----------------
extern "C" void kernel_launch(void* const* d_in, const int* in_sizes, int n_in,
                              void* d_out, int out_size, void* d_ws, size_t ws_size,
                              hipStream_t stream) {
  const float* patches   = (const float*)d_in[0];
  const int*   labels    = (const int*)d_in[1];
  const float* W_patch   = (const float*)d_in[2];
  const float* b_patch   = (const float*)d_in[3];
  const float* pos       = (const float*)d_in[4];
  const float* scale_emb = (const float*)d_in[5];
  const float* class_emb = (const float*)d_in[6];
  const float* ada_W     = (const float*)d_in[7];
  const float* ada_b     = (const float*)d_in[8];
  const float* qkv_W     = (const float*)d_in[9];
  const float* qkv_b     = (const float*)d_in[10];
  const float* q_scale   = (const float*)d_in[11];
  const float* proj_W    = (const float*)d_in[12];
  const float* proj_b    = (const float*)d_in[13];
  const float* fc1_W     = (const float*)d_in[14];
  const float* fc1_b     = (const float*)d_in[15];
  const float* fc2_W     = (const float*)d_in[16];
  const float* fc2_b     = (const float*)d_in[17];
  const float* hada_W    = (const float*)d_in[18];
  const float* hada_b    = (const float*)d_in[19];
  const float* head_W    = (const float*)d_in[20];
  const float* head_b    = (const float*)d_in[21];
  (void)in_sizes; (void)n_in; (void)out_size; (void)ws_size;

  char* wsb = (char*)d_ws;
  size_t off = 0;
  auto alloc = [&](size_t bytes) -> void* {
    void* p = wsb + off;
    off = (off + bytes + 255) & ~(size_t)255;
    return p;
  };

  float*    f_cond   = (float*)alloc(8 * 1024 * 4);
  float*    f_ada    = (float*)alloc((size_t)8 * 8 * 6144 * 4);
  float*    f_hada   = (float*)alloc(8 * 2048 * 4);
  float*    f_x      = (float*)alloc((size_t)2728 * 1024 * 4);
  ushort_t* u_h      = (ushort_t*)alloc((size_t)2728 * 1024 * 2);
  ushort_t* u_qkv    = (ushort_t*)alloc((size_t)2728 * 3072 * 2);
  ushort_t* u_o      = (ushort_t*)alloc((size_t)2728 * 1024 * 2);
  ushort_t* u_mid    = (ushort_t*)alloc((size_t)2728 * 4096 * 2);
  ushort_t* u_part   = (ushort_t*)alloc((size_t)2 * 2728 * 1024 * 2);
  float*    f_part   = (float*)alloc((size_t)4 * 2728 * 192 * 4);
  ushort_t* u_patch  = (ushort_t*)alloc((size_t)2720 * 192 * 2);
  ushort_t* u_qkvt   = (ushort_t*)alloc((size_t)8 * 3072 * 1024 * 2);
  ushort_t* u_projt  = (ushort_t*)alloc((size_t)8 * 1024 * 1024 * 2);
  ushort_t* u_fc1t   = (ushort_t*)alloc((size_t)8 * 4096 * 1024 * 2);
  ushort_t* u_fc2t   = (ushort_t*)alloc((size_t)8 * 1024 * 4096 * 2);
  ushort_t* u_wpt    = (ushort_t*)alloc((size_t)1024 * 192 * 2);
  ushort_t* u_wht    = (ushort_t*)alloc((size_t)192 * 1024 * 2);

  const int MT = 22;   // ceil(2728/128)
  const int MT64 = 43; // ceil(2728/64)

  k_cond_x0<<<8, 256, 0, stream>>>(labels, class_emb, pos, scale_emb, f_cond, f_x);
  k_transpose<<<dim3(32, 6, 1), 256, 0, stream>>>(W_patch, u_wpt, 192, 1024);
  k_transpose<<<dim3(6, 32, 1), 256, 0, stream>>>(head_W, u_wht, 1024, 192);
  k_convert<<<510, 256, 0, stream>>>(patches, u_patch, 130560);
  k_ada<<<dim3(96, 9), 256, 0, stream>>>(f_cond, ada_W, ada_b, hada_W, hada_b, f_ada, f_hada);
  k_transpose<<<dim3(96, 32, 8), 256, 0, stream>>>(qkv_W, u_qkvt, 1024, 3072);
  k_transpose<<<dim3(32, 32, 8), 256, 0, stream>>>(proj_W, u_projt, 1024, 1024);
  k_transpose<<<dim3(128, 32, 8), 256, 0, stream>>>(fc1_W, u_fc1t, 1024, 4096);
  k_transpose<<<dim3(32, 128, 8), 256, 0, stream>>>(fc2_W, u_fc2t, 4096, 1024);

  k_gemm<4, 128><<<dim3(8, MT), 256, 0, stream>>>(u_patch, u_wpt, b_patch, nullptr, nullptr,
                                                  nullptr, f_x, pos, scale_emb, 2720, 1024, 192, 192);
  // layer 0 LN1
  k_ln<<<2728, 256, 0, stream>>>(f_x, u_h, f_ada, 6144, 2048, 4096);

  for (int i = 0; i < 8; ++i) {
    const float* adaL = f_ada + (size_t)i * 8 * 6144;
    k_gemm<6, 128><<<dim3(24, MT), 256, 0, stream>>>(u_h, u_qkvt + (size_t)i * 3072 * 1024,
                                                     qkv_b + (size_t)i * 3072, nullptr, u_qkv,
                                                     q_scale + (size_t)i * 16, nullptr, nullptr,
                                                     nullptr, 2728, 3072, 1024, 1024);
    k_attn<<<dim3(6, 16, 8), 256, 0, stream>>>(u_qkv, u_o);
    k_gemm<1, 64><<<dim3(8, MT64, 1), 256, 0, stream>>>(u_o, u_projt + (size_t)i * 1024 * 1024,
                                                        proj_b + (size_t)i * 1024, nullptr,
                                                        nullptr, adaL, f_x, nullptr, nullptr,
                                                        2728, 1024, 1024, 1024);
    k_ln<<<2728, 256, 0, stream>>>(f_x, u_h, adaL, 6144, 3072, 5120);
    k_gemm<2, 128><<<dim3(32, MT), 256, 0, stream>>>(u_h, u_fc1t + (size_t)i * 4096 * 1024,
                                                     fc1_b + (size_t)i * 4096, nullptr,
                                                     u_mid, nullptr, nullptr, nullptr, nullptr,
                                                     2728, 4096, 1024, 1024);
    // fc2 split-K=2 -> bf16 partials
    k_gemm<8, 64><<<dim3(8, MT64, 2), 256, 0, stream>>>(u_mid, u_fc2t + (size_t)i * 4096 * 1024,
                                                        nullptr, nullptr, u_part, nullptr,
                                                        nullptr, nullptr, nullptr,
                                                        2728, 1024, 4096, 2048);
    if (i < 7) {
      k_comb_ln<<<2728, 256, 0, stream>>>(u_part, fc2_b + (size_t)i * 1024, adaL, 1024,
                                          f_x, f_ada + (size_t)(i + 1) * 8 * 6144,
                                          6144, 2048, 4096, u_h);
    } else {
      k_comb_ln<<<2728, 256, 0, stream>>>(u_part, fc2_b + (size_t)i * 1024, adaL, 1024,
                                          f_x, f_hada, 2048, 0, 1024, u_h);
    }
  }

  k_gemm<7, 64><<<dim3(2, MT64, 4), 256, 0, stream>>>(u_h, u_wht, nullptr, f_part, nullptr,
                                                      nullptr, nullptr, nullptr, nullptr,
                                                      2728, 192, 1024, 256);
  k_comb_head<<<2728, 256, 0, stream>>>(f_part, head_b, (float*)d_out, 4);
}

// Round 13
// 1746.545 us; speedup vs baseline: 1.0890x; 1.0117x over previous
//
#include <hip/hip_runtime.h>

typedef unsigned short ushort_t;
typedef __bf16 bf16x8 __attribute__((ext_vector_type(8)));
typedef float f32x4 __attribute__((ext_vector_type(4)));

#define DEV __device__ __forceinline__

DEV ushort_t f2bf(float x) {
  union { float f; unsigned u; } v; v.f = x;
  unsigned r = v.u + 0x7FFFu + ((v.u >> 16) & 1u);
  return (ushort_t)(r >> 16);
}
DEV float bf2f(ushort_t h) {
  union { unsigned u; float f; } v; v.u = (unsigned)h << 16;
  return v.f;
}
DEV int sid_of(int l) { return l < 5 ? 0 : (l < 21 ? 1 : (l < 85 ? 2 : 3)); }
DEV float fast_tanh(float u) { return 1.0f - 2.0f / (__expf(2.0f * u) + 1.0f); }
DEV float gelu_f(float x) {
  float u = 0.7978845608028654f * (x + 0.044715f * x * x * x);
  return 0.5f * x * (1.0f + fast_tanh(u));
}
DEV float silu_f(float x) { return x / (1.0f + __expf(-x)); }
DEV f32x4 mfma16(bf16x8 a, bf16x8 b, f32x4 c) {
  return __builtin_amdgcn_mfma_f32_16x16x32_bf16(a, b, c, 0, 0, 0);
}
DEV void gload16(const void* src, void* dst) {
  __builtin_amdgcn_global_load_lds(
      (const __attribute__((address_space(1))) void*)(uintptr_t)src,
      (__attribute__((address_space(3))) void*)(uintptr_t)dst, 16, 0, 0);
}

// ---------------- cond gather + x row 0 (x now bf16) ----------------
__global__ __launch_bounds__(256) void k_cond_x0(
    const int* __restrict__ labels, const float* __restrict__ class_emb,
    const float* __restrict__ pos, const float* __restrict__ semb,
    float* __restrict__ cond, ushort_t* __restrict__ x) {
  int b = blockIdx.x, t = threadIdx.x;
  int lab = labels[b];
  float4 cv = *(const float4*)&class_emb[(size_t)lab * 1024 + t * 4];
  *(float4*)&cond[(size_t)b * 1024 + t * 4] = cv;
  float4 pv = *(const float4*)&pos[t * 4];
  float4 sv = *(const float4*)&semb[t * 4];
  uint2 pk;
  pk.x = (unsigned)f2bf(cv.x + pv.x + sv.x) | ((unsigned)f2bf(cv.y + pv.y + sv.y) << 16);
  pk.y = (unsigned)f2bf(cv.z + pv.z + sv.z) | ((unsigned)f2bf(cv.w + pv.w + sv.w) << 16);
  *(uint2*)&x[(size_t)b * 341 * 1024 + t * 4] = pk;
}

// ---------------- f32 -> bf16 convert ----------------
__global__ __launch_bounds__(256) void k_convert(const float* __restrict__ src,
                                                 ushort_t* __restrict__ dst, int n4) {
  int i = blockIdx.x * 256 + threadIdx.x;
  if (i < n4) {
    float4 v = *(const float4*)&src[(size_t)i * 4];
    uint2 pk;
    pk.x = (unsigned)f2bf(v.x) | ((unsigned)f2bf(v.y) << 16);
    pk.y = (unsigned)f2bf(v.z) | ((unsigned)f2bf(v.w) << 16);
    *(uint2*)&dst[(size_t)i * 4] = pk;
  }
}

// ---------------- transpose f32 [K][N] -> bf16 [N][K], batched over z ----------------
__global__ __launch_bounds__(256) void k_transpose(const float* __restrict__ src,
                                                   ushort_t* __restrict__ dst, int K, int N) {
  __shared__ ushort_t tile[32][33];
  int z = blockIdx.z;
  src += (size_t)z * K * N;
  dst += (size_t)z * K * N;
  int k0 = blockIdx.y * 32, n0 = blockIdx.x * 32;
  int t = threadIdx.x;
  int r = t >> 3, c = (t & 7) * 4;
  float4 v = *(const float4*)&src[(size_t)(k0 + r) * N + n0 + c];
  tile[r][c] = f2bf(v.x); tile[r][c + 1] = f2bf(v.y);
  tile[r][c + 2] = f2bf(v.z); tile[r][c + 3] = f2bf(v.w);
  __syncthreads();
  ushort_t o0 = tile[c][r], o1 = tile[c + 1][r], o2 = tile[c + 2][r], o3 = tile[c + 3][r];
  uint2 pk;
  pk.x = (unsigned)o0 | ((unsigned)o1 << 16);
  pk.y = (unsigned)o2 | ((unsigned)o3 << 16);
  *(uint2*)&dst[(size_t)(n0 + r) * K + k0 + c] = pk;
}

// ---------------- adaLN GEMM ----------------
__global__ __launch_bounds__(256) void k_ada(const float* __restrict__ cond,
    const float* __restrict__ ada_W, const float* __restrict__ ada_b,
    const float* __restrict__ hada_W, const float* __restrict__ hada_b,
    float* __restrict__ ada_out, float* __restrict__ hada_out) {
  int gy = blockIdx.y;
  bool head = (gy == 8);
  int Nw = head ? 2048 : 6144;
  int n0 = blockIdx.x * 64;
  if (n0 >= Nw) return;
  __shared__ float sc[8 * 1024];
  __shared__ float red[4][64][8];
  int t = threadIdx.x;
  for (int i = t; i < 2048; i += 256) {
    float4 cv = *(const float4*)&cond[(size_t)i * 4];
    float* d = &sc[i * 4];
    d[0] = silu_f(cv.x); d[1] = silu_f(cv.y); d[2] = silu_f(cv.z); d[3] = silu_f(cv.w);
  }
  __syncthreads();
  const float* W = head ? hada_W : ada_W + (size_t)gy * 1024 * 6144;
  const float* bs = head ? hada_b : ada_b + (size_t)gy * 6144;
  float* op = head ? hada_out : ada_out + (size_t)gy * 8 * 6144;
  int col = n0 + (t & 63), kq = t >> 6;
  float acc[8] = {0.f, 0.f, 0.f, 0.f, 0.f, 0.f, 0.f, 0.f};
  for (int k = kq * 256; k < kq * 256 + 256; ++k) {
    float wv = W[(size_t)k * Nw + col];
#pragma unroll
    for (int b2 = 0; b2 < 8; ++b2) acc[b2] += wv * sc[b2 * 1024 + k];
  }
#pragma unroll
  for (int b2 = 0; b2 < 8; ++b2) red[kq][t & 63][b2] = acc[b2];
  __syncthreads();
  if (t < 64) {
    int colc = n0 + t;
    float bias = bs[colc];
#pragma unroll
    for (int b2 = 0; b2 < 8; ++b2) {
      float v = red[0][t][b2] + red[1][t][b2] + red[2][t][b2] + red[3][t][b2] + bias;
      op[(size_t)b2 * Nw + colc] = v;
    }
  }
}

// ---------------- LN + modulate -> bf16 (bf16 x input) ----------------
__global__ __launch_bounds__(256) void k_ln(const ushort_t* __restrict__ x,
    ushort_t* __restrict__ hout, const float* __restrict__ ada,
    int stride, int soff, int shoff) {
  int row = blockIdx.x, t = threadIdx.x;
  int b = row / 341;
  uint2 xv2 = *(const uint2*)&x[(size_t)row * 1024 + t * 4];
  float xe[4];
  xe[0] = bf2f((ushort_t)xv2.x);
  xe[1] = bf2f((ushort_t)(xv2.x >> 16));
  xe[2] = bf2f((ushort_t)xv2.y);
  xe[3] = bf2f((ushort_t)(xv2.y >> 16));
  float s = xe[0] + xe[1] + xe[2] + xe[3];
  float ss = xe[0] * xe[0] + xe[1] * xe[1] + xe[2] * xe[2] + xe[3] * xe[3];
#pragma unroll
  for (int off = 1; off < 64; off <<= 1) { s += __shfl_xor(s, off); ss += __shfl_xor(ss, off); }
  __shared__ float red[8];
  int w = t >> 6, lane = t & 63;
  if (lane == 0) { red[w] = s; red[w + 4] = ss; }
  __syncthreads();
  s = red[0] + red[1] + red[2] + red[3];
  ss = red[4] + red[5] + red[6] + red[7];
  float mean = s * (1.f / 1024.f);
  float var = ss * (1.f / 1024.f) - mean * mean;
  float rstd = rsqrtf(var + 1e-6f);
  const float* ar = ada + (size_t)b * stride;
  ushort_t tmp[4];
#pragma unroll
  for (int j = 0; j < 4; ++j) {
    int n = t * 4 + j;
    float val = (xe[j] - mean) * rstd * (1.f + ar[soff + n]) + ar[shoff + n];
    tmp[j] = f2bf(val);
  }
  uint2 pk;
  pk.x = (unsigned)tmp[0] | ((unsigned)tmp[1] << 16);
  pk.y = (unsigned)tmp[2] | ((unsigned)tmp[3] << 16);
  *(uint2*)&hout[(size_t)row * 1024 + t * 4] = pk;
}

// ---------------- fused residual-combine + LN + modulate (bf16 partials, bf16 x) ----------------
__global__ __launch_bounds__(256) void k_comb_ln(
    const ushort_t* __restrict__ p, const float* __restrict__ bias,
    const float* __restrict__ adag, int goff,
    ushort_t* __restrict__ x, const float* __restrict__ adaln,
    int lnstride, int soff, int shoff,
    ushort_t* __restrict__ hout) {
  int row = blockIdx.x, t = threadIdx.x;
  int b = row / 341;
  int c = t * 4;
  const ushort_t* pr = p + (size_t)row * 1024 + c;
  uint2 a0 = *(const uint2*)pr;
  uint2 a1 = *(const uint2*)(pr + (size_t)2728 * 1024);
  float s0 = bf2f((ushort_t)a0.x) + bf2f((ushort_t)a1.x);
  float s1 = bf2f((ushort_t)(a0.x >> 16)) + bf2f((ushort_t)(a1.x >> 16));
  float s2 = bf2f((ushort_t)a0.y) + bf2f((ushort_t)a1.y);
  float s3 = bf2f((ushort_t)(a0.y >> 16)) + bf2f((ushort_t)(a1.y >> 16));
  float4 bv = *(const float4*)&bias[c];
  const float* gr = adag + (size_t)b * 6144 + goff + c;
  ushort_t* xr = x + (size_t)row * 1024 + c;
  uint2 xv2 = *(uint2*)xr;
  float xe[4];
  xe[0] = bf2f((ushort_t)xv2.x)         + gr[0] * (s0 + bv.x);
  xe[1] = bf2f((ushort_t)(xv2.x >> 16)) + gr[1] * (s1 + bv.y);
  xe[2] = bf2f((ushort_t)xv2.y)         + gr[2] * (s2 + bv.z);
  xe[3] = bf2f((ushort_t)(xv2.y >> 16)) + gr[3] * (s3 + bv.w);
  uint2 xo;
  xo.x = (unsigned)f2bf(xe[0]) | ((unsigned)f2bf(xe[1]) << 16);
  xo.y = (unsigned)f2bf(xe[2]) | ((unsigned)f2bf(xe[3]) << 16);
  *(uint2*)xr = xo;
  float sm = xe[0] + xe[1] + xe[2] + xe[3];
  float ss = xe[0] * xe[0] + xe[1] * xe[1] + xe[2] * xe[2] + xe[3] * xe[3];
#pragma unroll
  for (int off = 1; off < 64; off <<= 1) { sm += __shfl_xor(sm, off); ss += __shfl_xor(ss, off); }
  __shared__ float red[8];
  int w = t >> 6, lane = t & 63;
  if (lane == 0) { red[w] = sm; red[w + 4] = ss; }
  __syncthreads();
  sm = red[0] + red[1] + red[2] + red[3];
  ss = red[4] + red[5] + red[6] + red[7];
  float mean = sm * (1.f / 1024.f);
  float var = ss * (1.f / 1024.f) - mean * mean;
  float rstd = rsqrtf(var + 1e-6f);
  const float* ar = adaln + (size_t)b * lnstride;
  ushort_t tmp[4];
#pragma unroll
  for (int j = 0; j < 4; ++j) {
    int n = c + j;
    float val = (xe[j] - mean) * rstd * (1.f + ar[soff + n]) + ar[shoff + n];
    tmp[j] = f2bf(val);
  }
  uint2 pk;
  pk.x = (unsigned)tmp[0] | ((unsigned)tmp[1] << 16);
  pk.y = (unsigned)tmp[2] | ((unsigned)tmp[3] << 16);
  *(uint2*)&hout[(size_t)row * 1024 + c] = pk;
}

// ---------------- main GEMM: 3-buffer / 1-barrier-per-K-step (R9, proven) ----------------
// EPI 1: x(bf16) += aux*v   EPI 2: bfout=gelu(v)  EPI 4: patch-embed (bf16 x)
// EPI 6: qkv+qknorm         EPI 7: f32 partial    EPI 8: bf16 partial
template <int EPI, int BM>
__global__ __launch_bounds__(256, 3) void k_gemm(
    const ushort_t* __restrict__ A, const ushort_t* __restrict__ Bt,
    const float* __restrict__ bias, float* __restrict__ fout,
    ushort_t* __restrict__ bfout, const float* __restrict__ aux,
    ushort_t* __restrict__ xres, const float* __restrict__ pos,
    const float* __restrict__ semb, int M, int N, int K, int KS) {
  constexpr int NI = (BM == 128) ? 4 : 2;
  constexpr int WNB = (BM == 128) ? 64 : 32;
  __shared__ ushort_t aT[3][BM * 32];
  __shared__ ushort_t bT[3][128 * 32];
  int tid = threadIdx.x;
  int lane = tid & 63, w = tid >> 6;
  int WR = (BM == 128) ? (w >> 1) : 0;
  int WC = (BM == 128) ? (w & 1) : w;

  int gx = gridDim.x;
  int nwg = gx * gridDim.y;
  int orig = blockIdx.y * gx + blockIdx.x;
  int q = nwg >> 3, r8 = nwg & 7;
  int xcd = orig & 7, idx = orig >> 3;
  int lin = (xcd < r8 ? xcd * (q + 1) : r8 * (q + 1) + (xcd - r8) * q) + idx;
  int bx = lin % gx, by = lin / gx;

  int m0 = by * BM, n0 = bx * 128;
  int kbase = blockIdx.z * KS;
  f32x4 acc[4][NI];
#pragma unroll
  for (int i = 0; i < 4; ++i)
#pragma unroll
    for (int j = 0; j < NI; ++j) acc[i][j] = (f32x4){0.f, 0.f, 0.f, 0.f};

  int lrow = lane & 15;
  int csw = (lrow >> 1) & 3;
  int coff = ((lane >> 4) ^ csw) * 8;

  int s_row0 = tid >> 2, s_u = tid & 3;
  int s_c = s_u ^ ((s_row0 >> 1) & 3);
  int aR0 = m0 + s_row0; if (aR0 > M - 1) aR0 = M - 1;
  int bR0 = n0 + s_row0; if (bR0 > N - 1) bR0 = N - 1;
  int aR1 = m0 + s_row0 + 64; if (aR1 > M - 1) aR1 = M - 1;
  int bR1 = n0 + s_row0 + 64; if (bR1 > N - 1) bR1 = N - 1;
  const ushort_t* aSrc0 = A + (size_t)aR0 * K + kbase + s_c * 8;
  const ushort_t* aSrc1 = A + (size_t)aR1 * K + kbase + s_c * 8;
  const ushort_t* bSrc0 = Bt + (size_t)bR0 * K + kbase + s_c * 8;
  const ushort_t* bSrc1 = Bt + (size_t)bR1 * K + kbase + s_c * 8;
  int slot0 = w * 512, slot1 = 2048 + w * 512;

  int nsteps = KS >> 5;
  auto STAGE = [&](int k0, int buf) {
    gload16(aSrc0 + k0, &aT[buf][slot0]);
    if constexpr (BM == 128) gload16(aSrc1 + k0, &aT[buf][slot1]);
    gload16(bSrc0 + k0, &bT[buf][slot0]);
    gload16(bSrc1 + k0, &bT[buf][slot1]);
  };

  STAGE(0, 0);
  int cur = 0;
  for (int s = 0; s < nsteps; ++s) {
    int nb = cur + 1; if (nb == 3) nb = 0;
    int kn = (s + 1 < nsteps) ? ((s + 1) << 5) : 0;  // wrap keeps vmcnt uniform
    STAGE(kn, nb);
    if constexpr (BM == 128)
      asm volatile("s_waitcnt vmcnt(4)" ::: "memory");
    else
      asm volatile("s_waitcnt vmcnt(3)" ::: "memory");
    __builtin_amdgcn_sched_barrier(0);
    __builtin_amdgcn_s_barrier();
    __builtin_amdgcn_sched_barrier(0);
    bf16x8 af[4], bb[NI];
#pragma unroll
    for (int mi = 0; mi < 4; ++mi)
      af[mi] = *(const bf16x8*)&aT[cur][(WR * 64 + mi * 16 + lrow) * 32 + coff];
#pragma unroll
    for (int ni = 0; ni < NI; ++ni)
      bb[ni] = *(const bf16x8*)&bT[cur][(WC * WNB + ni * 16 + lrow) * 32 + coff];
#pragma unroll
    for (int mi = 0; mi < 4; ++mi)
#pragma unroll
      for (int ni = 0; ni < NI; ++ni)
        acc[mi][ni] = mfma16(af[mi], bb[ni], acc[mi][ni]);
    cur = nb;  // 3-buffer rotation provides WAR safety
  }

  if constexpr (EPI == 6) {
    int nb = n0 + WC * 64;
    int gh = nb >> 6;
    float qse = (gh < 16) ? __expf(aux[gh]) : 1.0f;
    bool dn = gh < 32;
#pragma unroll
    for (int mi = 0; mi < 4; ++mi) {
#pragma unroll
      for (int r = 0; r < 4; ++r) {
        float vv[4]; float ss = 0.f;
#pragma unroll
        for (int ni = 0; ni < 4; ++ni) {
          vv[ni] = acc[mi][ni][r] + bias[nb + ni * 16 + lrow];
          ss += vv[ni] * vv[ni];
        }
        if (dn) {
          ss += __shfl_xor(ss, 1); ss += __shfl_xor(ss, 2);
          ss += __shfl_xor(ss, 4); ss += __shfl_xor(ss, 8);
          float rn = qse / fmaxf(sqrtf(ss), 1e-12f);
#pragma unroll
          for (int ni = 0; ni < 4; ++ni) vv[ni] *= rn;
        }
        int gm = m0 + WR * 64 + mi * 16 + (lane >> 4) * 4 + r;
        if (gm < M) {
#pragma unroll
          for (int ni = 0; ni < 4; ++ni)
            bfout[(size_t)gm * N + nb + ni * 16 + lrow] = f2bf(vv[ni]);
        }
      }
    }
  } else if constexpr (EPI == 1) {
#pragma unroll
    for (int mi = 0; mi < 4; ++mi) {
#pragma unroll
      for (int r = 0; r < 4; ++r) {
        int gm = m0 + WR * 64 + mi * 16 + (lane >> 4) * 4 + r;
        if (gm >= M) continue;
        int b = gm / 341;                 // hoisted: one division per row
        size_t xb = (size_t)gm * 1024;
        const float* ax = aux + (size_t)b * 6144;
#pragma unroll
        for (int ni = 0; ni < NI; ++ni) {
          int gn = n0 + WC * WNB + ni * 16 + lrow;
          if (gn >= N) continue;
          float xo = bf2f(xres[xb + gn]);
          xres[xb + gn] = f2bf(xo + ax[gn] * (acc[mi][ni][r] + bias[gn]));
        }
      }
    }
  } else {
#pragma unroll
    for (int mi = 0; mi < 4; ++mi) {
#pragma unroll
      for (int ni = 0; ni < NI; ++ni) {
#pragma unroll
        for (int r = 0; r < 4; ++r) {
          int gm = m0 + WR * 64 + mi * 16 + (lane >> 4) * 4 + r;
          int gn = n0 + WC * WNB + ni * 16 + lrow;
          if (gm >= M || gn >= N) continue;
          if constexpr (EPI == 7) {
            fout[(size_t)blockIdx.z * M * N + (size_t)gm * N + gn] = acc[mi][ni][r];
          } else if constexpr (EPI == 8) {
            bfout[(size_t)blockIdx.z * M * N + (size_t)gm * N + gn] = f2bf(acc[mi][ni][r]);
          } else {
            float v = acc[mi][ni][r] + bias[gn];
            if constexpr (EPI == 2) {
              bfout[(size_t)gm * N + gn] = f2bf(gelu_f(v));
            } else if constexpr (EPI == 4) {
              int b = gm / 340, l = gm % 340 + 1;
              float val = v + pos[(size_t)l * 1024 + gn] + semb[(size_t)sid_of(l) * 1024 + gn];
              xres[((size_t)(b * 341 + l)) * 1024 + gn] = f2bf(val);
            }
          }
        }
      }
    }
  }
}

// ---------------- split-K combine (head) ----------------
__global__ __launch_bounds__(256) void k_comb_head(const float* __restrict__ p,
    const float* __restrict__ bias, float* __restrict__ out, int nsplit) {
  int row = blockIdx.x, t = threadIdx.x;
  const int N = 192;
  size_t stride = (size_t)2728 * N;
  if (t < 48) {
    int c = t * 4;
    float4 s = *(const float4*)&p[(size_t)row * N + c];
    for (int sp = 1; sp < nsplit; ++sp) {
      float4 qq = *(const float4*)&p[sp * stride + (size_t)row * N + c];
      s.x += qq.x; s.y += qq.y; s.z += qq.z; s.w += qq.w;
    }
    float4 bv = *(const float4*)&bias[c];
    s.x += bv.x; s.y += bv.y; s.z += bv.z; s.w += bv.w;
    *(float4*)&out[(size_t)row * N + c] = s;
  }
}

// ---------------- fused flash attention (in-LDS V gather, defer-max) ----------------
__global__ __launch_bounds__(256) void k_attn(
    const ushort_t* __restrict__ qkv, ushort_t* __restrict__ o) {
  int qt = blockIdx.x, h = blockIdx.y, b = blockIdx.z;
  int t = threadIdx.x, lane = t & 63, w = t >> 6;
  int q0 = qt * 64;
  __shared__ ushort_t qT[64 * 72], kT[64 * 72], vS[64 * 72], vT[64 * 72];
  __shared__ ushort_t pT[4][16 * 72];
#pragma unroll
  for (int i = 0; i < 2; ++i) {
    int vid = t + 256 * i;
    int row = vid >> 3, seg = (vid & 7) * 8;
    int l = q0 + row; if (l > 340) l = 340;
    uint4 v = *(const uint4*)&qkv[((size_t)(b * 341 + l)) * 3072 + h * 64 + seg];
    *(uint4*)&qT[row * 72 + seg] = v;
  }
  int lrow = lane & 15, lk8 = (lane >> 4) * 8;
  int sq[4];
  float mrun[4], lsum[4];
  f32x4 accO[4];
#pragma unroll
  for (int r = 0; r < 4; ++r) {
    int lq = q0 + w * 16 + (lane >> 4) * 4 + r;
    sq[r] = sid_of(lq < 341 ? lq : 340);
    mrun[r] = -1e30f;
    lsum[r] = 0.f;
  }
#pragma unroll
  for (int d = 0; d < 4; ++d) accO[d] = (f32x4){0.f, 0.f, 0.f, 0.f};
  int nch = (qt == 0) ? 2 : 6;
  int vd = t >> 2, vlseg = (t & 3) * 16;
  for (int c = 0; c < nch; ++c) {
    __syncthreads();
#pragma unroll
    for (int i = 0; i < 2; ++i) {
      int vid = t + 256 * i;
      int row = vid >> 3, seg = (vid & 7) * 8;
      int l = c * 64 + row; if (l > 340) l = 340;
      size_t base = ((size_t)(b * 341 + l)) * 3072 + h * 64 + seg;
      uint4 kv = *(const uint4*)&qkv[base + 1024];
      uint4 vv = *(const uint4*)&qkv[base + 2048];
      *(uint4*)&kT[row * 72 + seg] = kv;
      *(uint4*)&vS[row * 72 + seg] = vv;
    }
    __syncthreads();
    ushort_t tmp[16];
#pragma unroll
    for (int j = 0; j < 16; ++j) tmp[j] = vS[(vlseg + j) * 72 + vd];
    f32x4 sf[4];
#pragma unroll
    for (int nf = 0; nf < 4; ++nf) sf[nf] = (f32x4){0.f, 0.f, 0.f, 0.f};
    __builtin_amdgcn_s_setprio(1);
#pragma unroll
    for (int ks = 0; ks < 2; ++ks) {
      bf16x8 aq = *(const bf16x8*)&qT[(w * 16 + lrow) * 72 + ks * 32 + lk8];
#pragma unroll
      for (int nf = 0; nf < 4; ++nf) {
        bf16x8 bk = *(const bf16x8*)&kT[(nf * 16 + lrow) * 72 + ks * 32 + lk8];
        sf[nf] = mfma16(aq, bk, sf[nf]);
      }
    }
    __builtin_amdgcn_s_setprio(0);
#pragma unroll
    for (int nf = 0; nf < 4; ++nf) {
      int lk = c * 64 + nf * 16 + lrow;
      int sk = lk < 341 ? sid_of(lk) : 9;
#pragma unroll
      for (int r = 0; r < 4; ++r)
        if (sk > sq[r]) sf[nf][r] = -1e30f;
    }
    float rs[4];
#pragma unroll
    for (int r = 0; r < 4; ++r) {
      float m = sf[0][r];
      m = fmaxf(m, sf[1][r]); m = fmaxf(m, sf[2][r]); m = fmaxf(m, sf[3][r]);
#pragma unroll
      for (int off = 1; off < 16; off <<= 1) m = fmaxf(m, __shfl_xor(m, off));
      // T13 defer-max: rescale only when chunk max exceeds running max + 8
      if (m > mrun[r] + 8.0f) {
        float scl = __expf(mrun[r] - m);
        mrun[r] = m;
        lsum[r] *= scl;
#pragma unroll
        for (int d = 0; d < 4; ++d) accO[d][r] *= scl;
      }
      rs[r] = 0.f;
    }
    ushort_t* pw = &pT[w][0];
#pragma unroll
    for (int nf = 0; nf < 4; ++nf) {
#pragma unroll
      for (int r = 0; r < 4; ++r) {
        float p = __expf(sf[nf][r] - mrun[r]);
        rs[r] += p;
        pw[((lane >> 4) * 4 + r) * 72 + nf * 16 + lrow] = f2bf(p);
      }
    }
#pragma unroll
    for (int r = 0; r < 4; ++r) {
      float sum = rs[r];
#pragma unroll
      for (int off = 1; off < 16; off <<= 1) sum += __shfl_xor(sum, off);
      lsum[r] += sum;
    }
    {
      uint4 s0, s1;
      s0.x = (unsigned)tmp[0] | ((unsigned)tmp[1] << 16);
      s0.y = (unsigned)tmp[2] | ((unsigned)tmp[3] << 16);
      s0.z = (unsigned)tmp[4] | ((unsigned)tmp[5] << 16);
      s0.w = (unsigned)tmp[6] | ((unsigned)tmp[7] << 16);
      s1.x = (unsigned)tmp[8] | ((unsigned)tmp[9] << 16);
      s1.y = (unsigned)tmp[10] | ((unsigned)tmp[11] << 16);
      s1.z = (unsigned)tmp[12] | ((unsigned)tmp[13] << 16);
      s1.w = (unsigned)tmp[14] | ((unsigned)tmp[15] << 16);
      *(uint4*)&vT[vd * 72 + vlseg] = s0;
      *(uint4*)&vT[vd * 72 + vlseg + 8] = s1;
    }
    __syncthreads();
    __builtin_amdgcn_s_setprio(1);
#pragma unroll
    for (int ks = 0; ks < 2; ++ks) {
      bf16x8 ap = *(const bf16x8*)&pw[lrow * 72 + ks * 32 + lk8];
#pragma unroll
      for (int d = 0; d < 4; ++d) {
        bf16x8 bv = *(const bf16x8*)&vT[(d * 16 + lrow) * 72 + ks * 32 + lk8];
        accO[d] = mfma16(ap, bv, accO[d]);
      }
    }
    __builtin_amdgcn_s_setprio(0);
  }
#pragma unroll
  for (int d = 0; d < 4; ++d) {
#pragma unroll
    for (int r = 0; r < 4; ++r) {
      int lq = q0 + w * 16 + (lane >> 4) * 4 + r;
      if (lq < 341) {
        float ov = accO[d][r] / fmaxf(lsum[r], 1e-30f);
        o[((size_t)(b * 341 + lq)) * 1024 + h * 64 + d * 16 + lrow] = f2bf(ov);
      }
    }
  }
}

// ---------------- launcher ----------------
extern "C" void kernel_launch(void* const* d_in, const int* in_sizes, int n_in,
                              void* d_out, int out_size, void* d_ws, size_t ws_size,
                              hipStream_t stream) {
  const float* patches   = (const float*)d_in[0];
  const int*   labels    = (const int*)d_in[1];
  const float* W_patch   = (const float*)d_in[2];
  const float* b_patch   = (const float*)d_in[3];
  const float* pos       = (const float*)d_in[4];
  const float* scale_emb = (const float*)d_in[5];
  const float* class_emb = (const float*)d_in[6];
  const float* ada_W     = (const float*)d_in[7];
  const float* ada_b     = (const float*)d_in[8];
  const float* qkv_W     = (const float*)d_in[9];
  const float* qkv_b     = (const float*)d_in[10];
  const float* q_scale   = (const float*)d_in[11];
  const float* proj_W    = (const float*)d_in[12];
  const float* proj_b    = (const float*)d_in[13];
  const float* fc1_W     = (const float*)d_in[14];
  const float* fc1_b     = (const float*)d_in[15];
  const float* fc2_W     = (const float*)d_in[16];
  const float* fc2_b     = (const float*)d_in[17];
  const float* hada_W    = (const float*)d_in[18];
  const float* hada_b    = (const float*)d_in[19];
  const float* head_W    = (const float*)d_in[20];
  const float* head_b    = (const float*)d_in[21];
  (void)in_sizes; (void)n_in; (void)out_size; (void)ws_size;

  char* wsb = (char*)d_ws;
  size_t off = 0;
  auto alloc = [&](size_t bytes) -> void* {
    void* p = wsb + off;
    off = (off + bytes + 255) & ~(size_t)255;
    return p;
  };

  float*    f_cond   = (float*)alloc(8 * 1024 * 4);
  float*    f_ada    = (float*)alloc((size_t)8 * 8 * 6144 * 4);
  float*    f_hada   = (float*)alloc(8 * 2048 * 4);
  ushort_t* u_x      = (ushort_t*)alloc((size_t)2728 * 1024 * 2);
  ushort_t* u_h      = (ushort_t*)alloc((size_t)2728 * 1024 * 2);
  ushort_t* u_qkv    = (ushort_t*)alloc((size_t)2728 * 3072 * 2);
  ushort_t* u_o      = (ushort_t*)alloc((size_t)2728 * 1024 * 2);
  ushort_t* u_mid    = (ushort_t*)alloc((size_t)2728 * 4096 * 2);
  ushort_t* u_part   = (ushort_t*)alloc((size_t)2 * 2728 * 1024 * 2);
  float*    f_part   = (float*)alloc((size_t)4 * 2728 * 192 * 4);
  ushort_t* u_patch  = (ushort_t*)alloc((size_t)2720 * 192 * 2);
  ushort_t* u_qkvt   = (ushort_t*)alloc((size_t)8 * 3072 * 1024 * 2);
  ushort_t* u_projt  = (ushort_t*)alloc((size_t)8 * 1024 * 1024 * 2);
  ushort_t* u_fc1t   = (ushort_t*)alloc((size_t)8 * 4096 * 1024 * 2);
  ushort_t* u_fc2t   = (ushort_t*)alloc((size_t)8 * 1024 * 4096 * 2);
  ushort_t* u_wpt    = (ushort_t*)alloc((size_t)1024 * 192 * 2);
  ushort_t* u_wht    = (ushort_t*)alloc((size_t)192 * 1024 * 2);

  const int MT = 22;   // ceil(2728/128)
  const int MT64 = 43; // ceil(2728/64)

  k_cond_x0<<<8, 256, 0, stream>>>(labels, class_emb, pos, scale_emb, f_cond, u_x);
  k_transpose<<<dim3(32, 6, 1), 256, 0, stream>>>(W_patch, u_wpt, 192, 1024);
  k_transpose<<<dim3(6, 32, 1), 256, 0, stream>>>(head_W, u_wht, 1024, 192);
  k_convert<<<510, 256, 0, stream>>>(patches, u_patch, 130560);
  k_ada<<<dim3(96, 9), 256, 0, stream>>>(f_cond, ada_W, ada_b, hada_W, hada_b, f_ada, f_hada);
  k_transpose<<<dim3(96, 32, 8), 256, 0, stream>>>(qkv_W, u_qkvt, 1024, 3072);
  k_transpose<<<dim3(32, 32, 8), 256, 0, stream>>>(proj_W, u_projt, 1024, 1024);
  k_transpose<<<dim3(128, 32, 8), 256, 0, stream>>>(fc1_W, u_fc1t, 1024, 4096);
  k_transpose<<<dim3(32, 128, 8), 256, 0, stream>>>(fc2_W, u_fc2t, 4096, 1024);

  k_gemm<4, 128><<<dim3(8, MT), 256, 0, stream>>>(u_patch, u_wpt, b_patch, nullptr, nullptr,
                                                  nullptr, u_x, pos, scale_emb, 2720, 1024, 192, 192);
  // layer 0 LN1
  k_ln<<<2728, 256, 0, stream>>>(u_x, u_h, f_ada, 6144, 2048, 4096);

  for (int i = 0; i < 8; ++i) {
    const float* adaL = f_ada + (size_t)i * 8 * 6144;
    k_gemm<6, 128><<<dim3(24, MT), 256, 0, stream>>>(u_h, u_qkvt + (size_t)i * 3072 * 1024,
                                                     qkv_b + (size_t)i * 3072, nullptr, u_qkv,
                                                     q_scale + (size_t)i * 16, nullptr, nullptr,
                                                     nullptr, 2728, 3072, 1024, 1024);
    k_attn<<<dim3(6, 16, 8), 256, 0, stream>>>(u_qkv, u_o);
    k_gemm<1, 64><<<dim3(8, MT64, 1), 256, 0, stream>>>(u_o, u_projt + (size_t)i * 1024 * 1024,
                                                        proj_b + (size_t)i * 1024, nullptr,
                                                        nullptr, adaL, u_x, nullptr, nullptr,
                                                        2728, 1024, 1024, 1024);
    k_ln<<<2728, 256, 0, stream>>>(u_x, u_h, adaL, 6144, 3072, 5120);
    k_gemm<2, 128><<<dim3(32, MT), 256, 0, stream>>>(u_h, u_fc1t + (size_t)i * 4096 * 1024,
                                                     fc1_b + (size_t)i * 4096, nullptr,
                                                     u_mid, nullptr, nullptr, nullptr, nullptr,
                                                     2728, 4096, 1024, 1024);
    // fc2 split-K=2 -> bf16 partials
    k_gemm<8, 64><<<dim3(8, MT64, 2), 256, 0, stream>>>(u_mid, u_fc2t + (size_t)i * 4096 * 1024,
                                                        nullptr, nullptr, u_part, nullptr,
                                                        nullptr, nullptr, nullptr,
                                                        2728, 1024, 4096, 2048);
    if (i < 7) {
      k_comb_ln<<<2728, 256, 0, stream>>>(u_part, fc2_b + (size_t)i * 1024, adaL, 1024,
                                          u_x, f_ada + (size_t)(i + 1) * 8 * 6144,
                                          6144, 2048, 4096, u_h);
    } else {
      k_comb_ln<<<2728, 256, 0, stream>>>(u_part, fc2_b + (size_t)i * 1024, adaL, 1024,
                                          u_x, f_hada, 2048, 0, 1024, u_h);
    }
  }

  k_gemm<7, 64><<<dim3(2, MT64, 4), 256, 0, stream>>>(u_h, u_wht, nullptr, f_part, nullptr,
                                                      nullptr, nullptr, nullptr, nullptr,
                                                      2728, 192, 1024, 256);
  k_comb_head<<<2728, 256, 0, stream>>>(f_part, head_b, (float*)d_out, 4);
}